// Round 19
// baseline (492.005 us; speedup 1.0000x reference)
//
#include <hip/hip_runtime.h>
#include <hip/hip_fp16.h>
#include <cstdint>
#include <cstddef>

typedef _Float16 f16;
typedef _Float16 f16x8 __attribute__((ext_vector_type(8)));
typedef _Float16 f16x4 __attribute__((ext_vector_type(4)));
typedef float    f32x4 __attribute__((ext_vector_type(4)));

#define MFMA(a, b, c) __builtin_amdgcn_mfma_f32_16x16x32_f16(a, b, c, 0, 0, 0)

// B=4, S=2048, D=1024, H=16, KS=VS=64, O=1024.

__device__ __forceinline__ void gload_lds16(const f16* g, f16* l) {
    __builtin_amdgcn_global_load_lds(
        (const __attribute__((address_space(1))) void*)g,
        (__attribute__((address_space(3))) void*)l, 16, 0, 0);
}

// ------------------- fp32 -> fp16 convert (Q,K,V fused) ----------------------
__global__ void k_convert3(const float* __restrict__ Q, const float* __restrict__ K,
                           const float* __restrict__ V, f16* __restrict__ Qh,
                           f16* __restrict__ Kh, f16* __restrict__ Vh) {
    const int seg = blockIdx.x >> 11;              // 0..2 (2048 blocks each)
    const int lb  = blockIdx.x & 2047;
    const float* src = seg == 0 ? Q : (seg == 1 ? K : V);
    f16* dst = seg == 0 ? Qh : (seg == 1 ? Kh : Vh);
    int i = lb * blockDim.x + threadIdx.x;
    for (; i < 2097152; i += 524288) {             // n4 = 8192*1024/4
        float4 v = ((const float4*)src)[i];
        f16x4 h;
        h[0] = (f16)v.x; h[1] = (f16)v.y; h[2] = (f16)v.z; h[3] = (f16)v.w;
        ((f16x4*)dst)[i] = h;
    }
}

// ---------------- weight transpose + convert to fp16 (all 4 fused) ----------
__global__ void k_transpose_all(const float* __restrict__ Wq, const float* __restrict__ Wk,
                                const float* __restrict__ Wv, const float* __restrict__ Wo,
                                f16* __restrict__ WT, f16* __restrict__ WoT) {
    __shared__ float T[64][65];
    const int bx = blockIdx.x;
    const int widx = bx >> 8, sub = bx & 255;
    const int nb = sub >> 4, db = sub & 15;
    const int tid = threadIdx.x;
    const float* W = widx == 0 ? Wq : (widx == 1 ? Wk : (widx == 2 ? Wv : Wo));
    f16* Wt = (widx < 3) ? (WT + (size_t)widx * 1048576) : WoT;
    const float* src = (widx < 3) ? (W + nb * 65536 + db * 4096)
                                  : (W + db * 65536 + nb * 64);
    const int rstride = (widx < 3) ? 64 : 1024;
    {
        int nn = tid & 63, d0 = tid >> 6;
#pragma unroll
        for (int p = 0; p < 16; ++p) {
            int dd = p * 4 + d0;
            T[dd][nn] = src[dd * rstride + nn];
        }
    }
    __syncthreads();
    {
        int dd = tid & 63, n0 = tid >> 6;
#pragma unroll
        for (int p = 0; p < 16; ++p) {
            int nn = p * 4 + n0;
            Wt[(size_t)(nb * 64 + nn) * 1024 + db * 64 + dd] = (f16)T[dd][nn];
        }
    }
}

// ---------------------- 256x128-tile GEMM building blocks --------------------
#define G256_STAGE(AD, BD, ASRC, BSRC, KT)                                      \
    do {                                                                        \
        int ktc = (KT);                                                         \
        _Pragma("unroll")                                                       \
        for (int i2 = 0; i2 < 4; ++i2) {                                        \
            int gA = wid * 4 + i2;                                              \
            gload_lds16(&(ASRC)[(size_t)(row0 + gA * 8 + (lane >> 3)) * 1024    \
                                + ktc * 64 + (lane & 7) * 8],                   \
                        &(AD)[(gA * 68 + lane) * 8]);                           \
        }                                                                       \
        _Pragma("unroll")                                                       \
        for (int i2 = 0; i2 < 2; ++i2) {                                        \
            int gB = wid * 2 + i2;                                              \
            gload_lds16(&(BSRC)[(size_t)(col0 + gB * 8 + (lane >> 3)) * 1024    \
                                + ktc * 64 + (lane & 7) * 8],                   \
                        &(BD)[(gB * 68 + lane) * 8]);                           \
        }                                                                       \
    } while (0)

#define G256_COMPUTE(AB, BB)                                                    \
    do {                                                                        \
        _Pragma("unroll")                                                       \
        for (int kk = 0; kk < 2; ++kk) {                                        \
            f16x8 af[4], bf[4];                                                 \
            _Pragma("unroll")                                                   \
            for (int m = 0; m < 4; ++m) {                                       \
                int rw = wm * 64 + m * 16 + lr;                                 \
                af[m] = *(const f16x8*)&(AB)[((rw >> 3) * 68 + (rw & 7) * 8     \
                                              + kk * 4 + lg) * 8];              \
            }                                                                   \
            _Pragma("unroll")                                                   \
            for (int n = 0; n < 4; ++n) {                                       \
                int rw = wn * 64 + n * 16 + lr;                                 \
                bf[n] = *(const f16x8*)&(BB)[((rw >> 3) * 68 + (rw & 7) * 8     \
                                              + kk * 4 + lg) * 8];              \
            }                                                                   \
            _Pragma("unroll")                                                   \
            for (int m = 0; m < 4; ++m)                                         \
                _Pragma("unroll")                                               \
                for (int n = 0; n < 4; ++n)                                     \
                    acc[m][n] = MFMA(af[m], bf[n], acc[m][n]);                  \
        }                                                                       \
    } while (0)

#define G256_PIPELINE(ASRC, BSRC)                                              \
    int cur = 0, nx1 = 1, nx2 = 2;                                             \
    G256_STAGE(As3, Bs3, ASRC, BSRC, 0);                                       \
    for (int t = 0; t < 16; ++t) {                                             \
        int tn = t < 15 ? t + 1 : 15;                                          \
        G256_STAGE(As3 + nx1 * 17408, Bs3 + nx1 * 8704, ASRC, BSRC, tn);       \
        asm volatile("s_waitcnt vmcnt(6)" ::: "memory");                       \
        __builtin_amdgcn_sched_barrier(0);                                     \
        __builtin_amdgcn_s_barrier();                                          \
        __builtin_amdgcn_sched_barrier(0);                                     \
        const f16* Ab = As3 + cur * 17408;                                     \
        const f16* Bb = Bs3 + cur * 8704;                                      \
        G256_COMPUTE(Ab, Bb);                                                  \
        int tmp = cur; cur = nx1; nx1 = nx2; nx2 = tmp;                        \
    }

// --------------------------- fused q/k/v GEMM (256x128) ----------------------
__global__ __launch_bounds__(512, 1) void k_gemm_qkv256(
    const f16* __restrict__ Qh, const f16* __restrict__ Kh, const f16* __restrict__ Vh,
    const f16* __restrict__ WT, const float* __restrict__ bq,
    const float* __restrict__ bk, const float* __restrict__ bv,
    f16* __restrict__ qout, f16* __restrict__ kout, f16* __restrict__ vout, float SC) {
    __shared__ f16 As3[3 * 17408];
    __shared__ f16 Bs3[3 * 8704];
    const int yy = blockIdx.y;
    const int seg = yy >> 3;
    const f16* A    = seg == 0 ? Qh : (seg == 1 ? Kh : Vh);
    const f16* Bt   = WT + (size_t)seg * 1048576;
    const float* bias = seg == 0 ? bq : (seg == 1 ? bk : bv);
    const float scale = seg == 0 ? SC : 1.0f;

    const int tid = threadIdx.x;
    const int wid = tid >> 6, lane = tid & 63;
    const int wm = wid >> 1, wn = wid & 1;
    const int lr = lane & 15, lg = lane >> 4;
    const int row0 = blockIdx.x * 256, col0 = (yy & 7) * 128;

    f32x4 acc[4][4];
#pragma unroll
    for (int m = 0; m < 4; ++m)
#pragma unroll
        for (int n = 0; n < 4; ++n) acc[m][n] = (f32x4){0.f, 0.f, 0.f, 0.f};

    G256_PIPELINE(A, Bt)

#pragma unroll
    for (int m = 0; m < 4; ++m) {
#pragma unroll
        for (int n = 0; n < 4; ++n) {
            int col = col0 + wn * 64 + n * 16 + lr;
            float bv_ = bias[col];
            int rowb = row0 + wm * 64 + m * 16 + lg * 4;
            int srow = rowb & 2047;
            if (seg == 0) {
#pragma unroll
                for (int r = 0; r < 4; ++r) {
                    int row = rowb + r;
                    size_t a = ((size_t)((row >> 11) * 16 + (col >> 6)) * 2048 + (row & 2047)) * 64 + (col & 63);
                    qout[a] = (f16)((acc[m][n][r] + bv_) * scale);
                }
            } else if (seg == 1) {
                int ks5 = srow & 31;
                int p0 = ((ks5 >> 2) & 1) * 16 + (ks5 >> 3) * 4 + (ks5 & 3);
                size_t abase = (size_t)((rowb >> 11) * 16 + (col >> 6)) * 131072
                             + (size_t)(srow >> 5) * 2048
                             + (size_t)(p0 >> 4) * 512
                             + (size_t)((col & 63) >> 5) * 1024
                             + (size_t)((col & 31) >> 3) * 128
                             + (col & 7);
#pragma unroll
                for (int r = 0; r < 4; ++r)
                    kout[abase + (size_t)((p0 & 15) + r) * 8] = (f16)(acc[m][n][r] + bv_);
            } else {
                size_t a = (size_t)((rowb >> 11) * 16 + (col >> 6)) * 131072
                         + (size_t)(srow >> 5) * 2048
                         + (size_t)((col & 63) >> 4) * 512
                         + (size_t)((srow & 31) >> 3) * 128
                         + (size_t)(col & 15) * 8
                         + (srow & 7);
                f16x4 ov;
#pragma unroll
                for (int r = 0; r < 4; ++r) ov[r] = (f16)(acc[m][n][r] + bv_);
                *(f16x4*)&vout[a] = ov;
            }
        }
    }
}

// ------------------------------ output GEMM (256x128) ------------------------
__global__ __launch_bounds__(512, 1) void k_gemm_out256(const f16* __restrict__ A,
                                                        const f16* __restrict__ Bt,
                                                        const float* __restrict__ bias,
                                                        float* __restrict__ Cout) {
    __shared__ f16 As3[3 * 17408];
    __shared__ f16 Bs3[3 * 8704];
    const int tid = threadIdx.x;
    const int wid = tid >> 6, lane = tid & 63;
    const int wm = wid >> 1, wn = wid & 1;
    const int lr = lane & 15, lg = lane >> 4;
    const int row0 = blockIdx.x * 256, col0 = blockIdx.y * 128;

    f32x4 acc[4][4];
#pragma unroll
    for (int m = 0; m < 4; ++m)
#pragma unroll
        for (int n = 0; n < 4; ++n) acc[m][n] = (f32x4){0.f, 0.f, 0.f, 0.f};

    G256_PIPELINE(A, Bt)

#pragma unroll
    for (int m = 0; m < 4; ++m) {
#pragma unroll
        for (int n = 0; n < 4; ++n) {
            int col = col0 + wn * 64 + n * 16 + lr;
            float bv = bias[col];
#pragma unroll
            for (int r = 0; r < 4; ++r) {
                int row = row0 + wm * 64 + m * 16 + lg * 4 + r;
                Cout[(size_t)row * 1024 + col] = acc[m][n][r] + bv;
            }
        }
    }
}

// -------------------------- attention (split-K partial) ----------------------
// 8 waves x 32 q-rows x HALF the K range. LDS reads per unit work halved vs
// r18 (round-18 diagnosis: LDS-read pipe ~70% busy — 8 waves re-reading the
// same 8KB tile; 32q/wave makes 8 ds_reads serve 16 MFMA). Split-K x2 keeps
// grid at 1024 (4 blocks/CU x 8 waves -> up to 32 waves/CU at <=64 VGPR,
// cap 85 via (512,6)). Lane-major fragments (0 conflicts); 4-buffer pair
// staging (waves 0-3 K, 4-7 V); m folded into MFMA C-init; lazy max vs THR.
// Partials: po f16 [ks][bh*2048+q][64]; stats f32. Merge = r12's (verified).
#define ATTN_TILE(Kc, Vc)                                                     \
    do {                                                                      \
        f16x8 ka0 = *(const f16x8*)&(Kc)[fo];                                 \
        f16x8 ka1 = *(const f16x8*)&(Kc)[fo + 1024];                          \
        f16x8 ka2 = *(const f16x8*)&(Kc)[fo + 512];                           \
        f16x8 ka3 = *(const f16x8*)&(Kc)[fo + 1536];                          \
        f32x4 st[2][2];                                                       \
        _Pragma("unroll")                                                     \
        for (int qt = 0; qt < 2; ++qt) {                                      \
            float nm = -m_r[qt];                                              \
            f32x4 z = (f32x4){nm, nm, nm, nm};                                \
            z = MFMA(ka0, qf[qt][0], z);                                      \
            z = MFMA(ka1, qf[qt][1], z);                                      \
            st[qt][0] = z;                                                    \
            f32x4 z2 = (f32x4){nm, nm, nm, nm};                               \
            z2 = MFMA(ka2, qf[qt][0], z2);                                    \
            z2 = MFMA(ka3, qf[qt][1], z2);                                    \
            st[qt][1] = z2;                                                   \
        }                                                                     \
        f16x8 vv0 = *(const f16x8*)&(Vc)[fo];                                 \
        f16x8 vv1 = *(const f16x8*)&(Vc)[fo + 512];                           \
        f16x8 vv2 = *(const f16x8*)&(Vc)[fo + 1024];                          \
        f16x8 vv3 = *(const f16x8*)&(Vc)[fo + 1536];                          \
        {                                                                     \
            float lm[2];                                                      \
            _Pragma("unroll")                                                 \
            for (int qt = 0; qt < 2; ++qt) {                                  \
                float a0 = fmaxf(fmaxf(st[qt][0][0], st[qt][0][1]), st[qt][0][2]); \
                float b0 = fmaxf(fmaxf(st[qt][0][3], st[qt][1][0]), st[qt][1][1]); \
                float c0 = fmaxf(fmaxf(st[qt][1][2], st[qt][1][3]), a0);      \
                lm[qt] = fmaxf(b0, c0);                                       \
            }                                                                 \
            if (__any((lm[0] > THR) || (lm[1] > THR))) {                      \
                _Pragma("unroll")                                             \
                for (int qt = 0; qt < 2; ++qt) {                              \
                    float t0v = lm[qt];                                       \
                    t0v = fmaxf(t0v, __shfl_xor(t0v, 16, 64));                \
                    t0v = fmaxf(t0v, __shfl_xor(t0v, 32, 64));                \
                    float delta = fmaxf(0.f, t0v);                            \
                    float alpha = __builtin_amdgcn_exp2f(-delta);             \
                    _Pragma("unroll")                                         \
                    for (int m = 0; m < 4; ++m)                               \
                        _Pragma("unroll")                                     \
                        for (int r = 0; r < 4; ++r) o[qt][m][r] *= alpha;     \
                    l_p[qt] *= alpha;                                         \
                    m_r[qt] += delta;                                         \
                    _Pragma("unroll")                                         \
                    for (int t = 0; t < 2; ++t)                               \
                        _Pragma("unroll")                                     \
                        for (int r = 0; r < 4; ++r) st[qt][t][r] -= delta;    \
                }                                                             \
            }                                                                 \
        }                                                                     \
        f16x8 pf[2];                                                          \
        _Pragma("unroll")                                                     \
        for (int qt = 0; qt < 2; ++qt) {                                      \
            float ps = 0.f;                                                   \
            union { uint32_t u[4]; f16x8 v; } bb;                             \
            _Pragma("unroll")                                                 \
            for (int t = 0; t < 2; ++t)                                       \
                _Pragma("unroll")                                             \
                for (int pr = 0; pr < 2; ++pr) {                              \
                    float e0 = __builtin_amdgcn_exp2f(st[qt][t][2 * pr]);     \
                    float e1 = __builtin_amdgcn_exp2f(st[qt][t][2 * pr + 1]); \
                    ps += e0 + e1;                                            \
                    auto hp = __builtin_amdgcn_cvt_pkrtz(e0, e1);             \
                    bb.u[t * 2 + pr] = __builtin_bit_cast(uint32_t, hp);      \
                }                                                             \
            l_p[qt] += ps;                                                    \
            pf[qt] = bb.v;                                                    \
        }                                                                     \
        _Pragma("unroll")                                                     \
        for (int qt = 0; qt < 2; ++qt) {                                      \
            o[qt][0] = MFMA(vv0, pf[qt], o[qt][0]);                           \
            o[qt][1] = MFMA(vv1, pf[qt], o[qt][1]);                           \
            o[qt][2] = MFMA(vv2, pf[qt], o[qt][2]);                           \
            o[qt][3] = MFMA(vv3, pf[qt], o[qt][3]);                           \
        }                                                                     \
    } while (0)

__global__ __launch_bounds__(512, 6) void k_attn_part(const f16* __restrict__ q,
                                                      const f16* __restrict__ k2,
                                                      const f16* __restrict__ v2,
                                                      f16* __restrict__ po,
                                                      float* __restrict__ sm,
                                                      float* __restrict__ sl) {
    const int g = blockIdx.x;                 // 0..1023
    const int xcd = g & 7, i = g >> 3;        // i: 0..127
    const int bh = xcd * 8 + (i >> 4);        // 8 bh per XCD (K/V L2 locality)
    const int rr = i & 15;
    const int qb = rr & 7;                    // 8 q-blocks of 256 rows
    const int ks = rr >> 3;                   // K-half 0/1

    const int tid = threadIdx.x, wid = tid >> 6, lane = tid & 63;
    const int lr = lane & 15, lg = lane >> 4;
    const int qw = qb * 256 + wid * 32;       // this wave's 32 q-rows

    __shared__ f16 Ks[4][2048];
    __shared__ f16 Vs[4][2048];

    const float THR = 8.0f;

    f16x8 qf[2][2];
#pragma unroll
    for (int qt = 0; qt < 2; ++qt)
#pragma unroll
        for (int hf = 0; hf < 2; ++hf)
            qf[qt][hf] = *(const f16x8*)&q[((size_t)bh * 2048 + qw + qt * 16 + lr) * 64 + hf * 32 + lg * 8];

    const f16* kt = k2 + (size_t)bh * 131072 + (size_t)ks * 65536;
    const f16* vt = v2 + (size_t)bh * 131072 + (size_t)ks * 65536;
    const bool sgK = (tid < 256);             // waves 0-3 stage K, 4-7 stage V
    const int so2 = (tid & 255) * 8;
    const int fo = lane * 8;

    f32x4 o[2][4];
#pragma unroll
    for (int qt = 0; qt < 2; ++qt)
#pragma unroll
        for (int m = 0; m < 4; ++m) o[qt][m] = (f32x4){0.f, 0.f, 0.f, 0.f};
    float m_r[2] = {0.f, 0.f}, l_p[2] = {0.f, 0.f};

    // prologue: stage tiles 0,1 of this K-half
    if (sgK) {
        gload_lds16(kt + so2, &Ks[0][so2]);
        gload_lds16(kt + 2048 + so2, &Ks[1][so2]);
    } else {
        gload_lds16(vt + so2, &Vs[0][so2]);
        gload_lds16(vt + 2048 + so2, &Vs[1][so2]);
    }
    __syncthreads();

    // pair loop: 32 tiles per half; 1 barrier per 2 tiles
    for (int pp = 0; pp < 16; ++pp) {
        const int t0 = 2 * pp;
        const int ba = t0 & 3, bb2 = (t0 + 1) & 3;
        const int bc = (t0 + 2) & 3, bd = (t0 + 3) & 3;

        // tail stages read up to 2 tiles past this half: same-bh other half /
        // adjacent ws buffer — in-bounds of d_ws, never consumed
        if (sgK) {
            gload_lds16(kt + (size_t)(t0 + 2) * 2048 + so2, &Ks[bc][so2]);
            gload_lds16(kt + (size_t)(t0 + 3) * 2048 + so2, &Ks[bd][so2]);
        } else {
            gload_lds16(vt + (size_t)(t0 + 2) * 2048 + so2, &Vs[bc][so2]);
            gload_lds16(vt + (size_t)(t0 + 3) * 2048 + so2, &Vs[bd][so2]);
        }

        ATTN_TILE(&Ks[ba][0], &Vs[ba][0]);
        ATTN_TILE(&Ks[bb2][0], &Vs[bb2][0]);

        __syncthreads();
    }

    // epilogue: reduce per-lane l partials; store po (f16) + per-row stats
#pragma unroll
    for (int qt = 0; qt < 2; ++qt) {
        float l = l_p[qt];
        l += __shfl_xor(l, 16, 64);
        l += __shfl_xor(l, 32, 64);
        int R = bh * 2048 + qw + qt * 16 + lr;
        size_t pb = ((size_t)ks * 131072 + R) * 64 + lg * 4;
#pragma unroll
        for (int m = 0; m < 4; ++m) {
            f16x4 ov;
#pragma unroll
            for (int r = 0; r < 4; ++r) ov[r] = (f16)o[qt][m][r];
            *(f16x4*)&po[pb + m * 16] = ov;
        }
        if (lg == 0) {
            sm[ks * 131072 + R] = m_r[qt];
            sl[ks * 131072 + R] = l;
        }
    }
}

// ------------------------------ split-K merge --------------------------------
__global__ void k_merge(const f16* __restrict__ po, const float* __restrict__ sm,
                        const float* __restrict__ sl, f16* __restrict__ cat) {
    const int tid = threadIdx.x;
    const int R = blockIdx.x * 32 + (tid >> 3);
    const int vd8 = (tid & 7) * 8;
    const int bh = R >> 11, srow = R & 2047;
    const int b = bh >> 4, h = bh & 15;
    float m0 = sm[R], m1 = sm[131072 + R];
    float l0 = sl[R], l1 = sl[131072 + R];
    float M = fmaxf(m0, m1);
    float w0 = __builtin_amdgcn_exp2f(m0 - M);
    float w1 = __builtin_amdgcn_exp2f(m1 - M);
    float inv = 1.f / (l0 * w0 + l1 * w1);
    w0 *= inv; w1 *= inv;
    f16x8 p0 = *(const f16x8*)&po[(size_t)R * 64 + vd8];
    f16x8 p1 = *(const f16x8*)&po[((size_t)131072 + R) * 64 + vd8];
    f16x8 outv;
#pragma unroll
    for (int j = 0; j < 8; ++j)
        outv[j] = (f16)((float)p0[j] * w0 + (float)p1[j] * w1);
    *(f16x8*)&cat[((size_t)b * 2048 + srow) * 1024 + h * 64 + vd8] = outv;
}

// ---------------------------------------------------------------------------
extern "C" void kernel_launch(void* const* d_in, const int* in_sizes, int n_in,
                              void* d_out, int out_size, void* d_ws, size_t ws_size,
                              hipStream_t stream) {
    const float* Q  = (const float*)d_in[0];
    const float* K  = (const float*)d_in[1];
    const float* V  = (const float*)d_in[2];
    const float* Wq = (const float*)d_in[3];
    const float* bq = (const float*)d_in[4];
    const float* Wk = (const float*)d_in[5];
    const float* bk = (const float*)d_in[6];
    const float* Wv = (const float*)d_in[7];
    const float* bv = (const float*)d_in[8];
    const float* Wo = (const float*)d_in[9];
    const float* bo = (const float*)d_in[10];

    char* ws = (char*)d_ws;
    size_t off = 0;
    auto alloc = [&](size_t bytes) {
        char* p = ws + off;
        off += (bytes + 255) & ~(size_t)255;
        return p;
    };
    f16* Qh  = (f16*)alloc(8192ULL * 1024 * 2);
    f16* Kh  = (f16*)alloc(8192ULL * 1024 * 2);
    f16* Vh  = (f16*)alloc(8192ULL * 1024 * 2);
    f16* WT  = (f16*)alloc(3ULL * 1024 * 1024 * 2);   // WqT|WkT|WvT contiguous
    f16* WoT = (f16*)alloc(1024ULL * 1024 * 2);
    f16* qb  = (f16*)alloc(8192ULL * 1024 * 2);   // head-major [(b,h)][s][64]
    f16* kb2 = (f16*)alloc(8192ULL * 1024 * 2);   // [bh][tile] lane-major perm K
    f16* vb2 = (f16*)alloc(8192ULL * 1024 * 2);   // [bh][tile] lane-major V^T
    f16* cat = (f16*)alloc(8192ULL * 1024 * 2);   // [B*S][H*VS]
    f16* po  = (f16*)alloc(2ULL * 131072 * 64 * 2);   // split-K partial O
    float* sm = (float*)alloc(2ULL * 131072 * 4);     // split-K partial max
    float* sl = (float*)alloc(2ULL * 131072 * 4);     // split-K partial l

    k_convert3<<<6144, 256, 0, stream>>>(Q, K, V, Qh, Kh, Vh);
    k_transpose_all<<<1024, 256, 0, stream>>>(Wq, Wk, Wv, Wo, WT, WoT);

    const float SC = 0.125f * 1.44269504089f;   // 1/sqrt(64) * log2(e), folded into q
    k_gemm_qkv256<<<dim3(32, 24), 512, 0, stream>>>(Qh, Kh, Vh, WT, bq, bk, bv,
                                                    qb, kb2, vb2, SC);

    k_attn_part<<<1024, 512, 0, stream>>>(qb, kb2, vb2, po, sm, sl);
    k_merge<<<4096, 256, 0, stream>>>(po, sm, sl, cat);

    k_gemm_out256<<<dim3(32, 8), 512, 0, stream>>>(cat, WoT, bo, (float*)d_out);
}

// Round 20
// 193.548 us; speedup vs baseline: 2.5420x; 2.5420x over previous
//
#include <hip/hip_runtime.h>
#include <hip/hip_fp16.h>
#include <cstdint>
#include <cstddef>

typedef _Float16 f16;
typedef _Float16 f16x8 __attribute__((ext_vector_type(8)));
typedef _Float16 f16x4 __attribute__((ext_vector_type(4)));
typedef float    f32x4 __attribute__((ext_vector_type(4)));

#define MFMA(a, b, c) __builtin_amdgcn_mfma_f32_16x16x32_f16(a, b, c, 0, 0, 0)

// B=4, S=2048, D=1024, H=16, KS=VS=64, O=1024.

__device__ __forceinline__ void gload_lds16(const f16* g, f16* l) {
    __builtin_amdgcn_global_load_lds(
        (const __attribute__((address_space(1))) void*)g,
        (__attribute__((address_space(3))) void*)l, 16, 0, 0);
}

// ------------------- fp32 -> fp16 convert (Q,K,V fused) ----------------------
__global__ void k_convert3(const float* __restrict__ Q, const float* __restrict__ K,
                           const float* __restrict__ V, f16* __restrict__ Qh,
                           f16* __restrict__ Kh, f16* __restrict__ Vh) {
    const int seg = blockIdx.x >> 11;              // 0..2 (2048 blocks each)
    const int lb  = blockIdx.x & 2047;
    const float* src = seg == 0 ? Q : (seg == 1 ? K : V);
    f16* dst = seg == 0 ? Qh : (seg == 1 ? Kh : Vh);
    int i = lb * blockDim.x + threadIdx.x;
    for (; i < 2097152; i += 524288) {             // n4 = 8192*1024/4
        float4 v = ((const float4*)src)[i];
        f16x4 h;
        h[0] = (f16)v.x; h[1] = (f16)v.y; h[2] = (f16)v.z; h[3] = (f16)v.w;
        ((f16x4*)dst)[i] = h;
    }
}

// ---------------- weight transpose + convert to fp16 (all 4 fused) ----------
__global__ void k_transpose_all(const float* __restrict__ Wq, const float* __restrict__ Wk,
                                const float* __restrict__ Wv, const float* __restrict__ Wo,
                                f16* __restrict__ WT, f16* __restrict__ WoT) {
    __shared__ float T[64][65];
    const int bx = blockIdx.x;
    const int widx = bx >> 8, sub = bx & 255;
    const int nb = sub >> 4, db = sub & 15;
    const int tid = threadIdx.x;
    const float* W = widx == 0 ? Wq : (widx == 1 ? Wk : (widx == 2 ? Wv : Wo));
    f16* Wt = (widx < 3) ? (WT + (size_t)widx * 1048576) : WoT;
    const float* src = (widx < 3) ? (W + nb * 65536 + db * 4096)
                                  : (W + db * 65536 + nb * 64);
    const int rstride = (widx < 3) ? 64 : 1024;
    {
        int nn = tid & 63, d0 = tid >> 6;
#pragma unroll
        for (int p = 0; p < 16; ++p) {
            int dd = p * 4 + d0;
            T[dd][nn] = src[dd * rstride + nn];
        }
    }
    __syncthreads();
    {
        int dd = tid & 63, n0 = tid >> 6;
#pragma unroll
        for (int p = 0; p < 16; ++p) {
            int nn = p * 4 + n0;
            Wt[(size_t)(nb * 64 + nn) * 1024 + db * 64 + dd] = (f16)T[dd][nn];
        }
    }
}

// ---------------------- 256x128-tile GEMM building blocks --------------------
#define G256_STAGE(AD, BD, ASRC, BSRC, KT)                                      \
    do {                                                                        \
        int ktc = (KT);                                                         \
        _Pragma("unroll")                                                       \
        for (int i2 = 0; i2 < 4; ++i2) {                                        \
            int gA = wid * 4 + i2;                                              \
            gload_lds16(&(ASRC)[(size_t)(row0 + gA * 8 + (lane >> 3)) * 1024    \
                                + ktc * 64 + (lane & 7) * 8],                   \
                        &(AD)[(gA * 68 + lane) * 8]);                           \
        }                                                                       \
        _Pragma("unroll")                                                       \
        for (int i2 = 0; i2 < 2; ++i2) {                                        \
            int gB = wid * 2 + i2;                                              \
            gload_lds16(&(BSRC)[(size_t)(col0 + gB * 8 + (lane >> 3)) * 1024    \
                                + ktc * 64 + (lane & 7) * 8],                   \
                        &(BD)[(gB * 68 + lane) * 8]);                           \
        }                                                                       \
    } while (0)

#define G256_COMPUTE(AB, BB)                                                    \
    do {                                                                        \
        _Pragma("unroll")                                                       \
        for (int kk = 0; kk < 2; ++kk) {                                        \
            f16x8 af[4], bf[4];                                                 \
            _Pragma("unroll")                                                   \
            for (int m = 0; m < 4; ++m) {                                       \
                int rw = wm * 64 + m * 16 + lr;                                 \
                af[m] = *(const f16x8*)&(AB)[((rw >> 3) * 68 + (rw & 7) * 8     \
                                              + kk * 4 + lg) * 8];              \
            }                                                                   \
            _Pragma("unroll")                                                   \
            for (int n = 0; n < 4; ++n) {                                       \
                int rw = wn * 64 + n * 16 + lr;                                 \
                bf[n] = *(const f16x8*)&(BB)[((rw >> 3) * 68 + (rw & 7) * 8     \
                                              + kk * 4 + lg) * 8];              \
            }                                                                   \
            _Pragma("unroll")                                                   \
            for (int m = 0; m < 4; ++m)                                         \
                _Pragma("unroll")                                               \
                for (int n = 0; n < 4; ++n)                                     \
                    acc[m][n] = MFMA(af[m], bf[n], acc[m][n]);                  \
        }                                                                       \
    } while (0)

#define G256_PIPELINE(ASRC, BSRC)                                              \
    int cur = 0, nx1 = 1, nx2 = 2;                                             \
    G256_STAGE(As3, Bs3, ASRC, BSRC, 0);                                       \
    for (int t = 0; t < 16; ++t) {                                             \
        int tn = t < 15 ? t + 1 : 15;                                          \
        G256_STAGE(As3 + nx1 * 17408, Bs3 + nx1 * 8704, ASRC, BSRC, tn);       \
        asm volatile("s_waitcnt vmcnt(6)" ::: "memory");                       \
        __builtin_amdgcn_sched_barrier(0);                                     \
        __builtin_amdgcn_s_barrier();                                          \
        __builtin_amdgcn_sched_barrier(0);                                     \
        const f16* Ab = As3 + cur * 17408;                                     \
        const f16* Bb = Bs3 + cur * 8704;                                      \
        G256_COMPUTE(Ab, Bb);                                                  \
        int tmp = cur; cur = nx1; nx1 = nx2; nx2 = tmp;                        \
    }

// --------------------------- fused q/k/v GEMM (256x128) ----------------------
__global__ __launch_bounds__(512, 1) void k_gemm_qkv256(
    const f16* __restrict__ Qh, const f16* __restrict__ Kh, const f16* __restrict__ Vh,
    const f16* __restrict__ WT, const float* __restrict__ bq,
    const float* __restrict__ bk, const float* __restrict__ bv,
    f16* __restrict__ qout, f16* __restrict__ kout, f16* __restrict__ vout, float SC) {
    __shared__ f16 As3[3 * 17408];
    __shared__ f16 Bs3[3 * 8704];
    const int yy = blockIdx.y;
    const int seg = yy >> 3;
    const f16* A    = seg == 0 ? Qh : (seg == 1 ? Kh : Vh);
    const f16* Bt   = WT + (size_t)seg * 1048576;
    const float* bias = seg == 0 ? bq : (seg == 1 ? bk : bv);
    const float scale = seg == 0 ? SC : 1.0f;

    const int tid = threadIdx.x;
    const int wid = tid >> 6, lane = tid & 63;
    const int wm = wid >> 1, wn = wid & 1;
    const int lr = lane & 15, lg = lane >> 4;
    const int row0 = blockIdx.x * 256, col0 = (yy & 7) * 128;

    f32x4 acc[4][4];
#pragma unroll
    for (int m = 0; m < 4; ++m)
#pragma unroll
        for (int n = 0; n < 4; ++n) acc[m][n] = (f32x4){0.f, 0.f, 0.f, 0.f};

    G256_PIPELINE(A, Bt)

#pragma unroll
    for (int m = 0; m < 4; ++m) {
#pragma unroll
        for (int n = 0; n < 4; ++n) {
            int col = col0 + wn * 64 + n * 16 + lr;
            float bv_ = bias[col];
            int rowb = row0 + wm * 64 + m * 16 + lg * 4;
            int srow = rowb & 2047;
            if (seg == 0) {
#pragma unroll
                for (int r = 0; r < 4; ++r) {
                    int row = rowb + r;
                    size_t a = ((size_t)((row >> 11) * 16 + (col >> 6)) * 2048 + (row & 2047)) * 64 + (col & 63);
                    qout[a] = (f16)((acc[m][n][r] + bv_) * scale);
                }
            } else if (seg == 1) {
                int ks5 = srow & 31;
                int p0 = ((ks5 >> 2) & 1) * 16 + (ks5 >> 3) * 4 + (ks5 & 3);
                size_t abase = (size_t)((rowb >> 11) * 16 + (col >> 6)) * 131072
                             + (size_t)(srow >> 5) * 2048
                             + (size_t)(p0 >> 4) * 512
                             + (size_t)((col & 63) >> 5) * 1024
                             + (size_t)((col & 31) >> 3) * 128
                             + (col & 7);
#pragma unroll
                for (int r = 0; r < 4; ++r)
                    kout[abase + (size_t)((p0 & 15) + r) * 8] = (f16)(acc[m][n][r] + bv_);
            } else {
                size_t a = (size_t)((rowb >> 11) * 16 + (col >> 6)) * 131072
                         + (size_t)(srow >> 5) * 2048
                         + (size_t)((col & 63) >> 4) * 512
                         + (size_t)((srow & 31) >> 3) * 128
                         + (size_t)(col & 15) * 8
                         + (srow & 7);
                f16x4 ov;
#pragma unroll
                for (int r = 0; r < 4; ++r) ov[r] = (f16)(acc[m][n][r] + bv_);
                *(f16x4*)&vout[a] = ov;
            }
        }
    }
}

// ------------------------------ output GEMM (256x128) ------------------------
__global__ __launch_bounds__(512, 1) void k_gemm_out256(const f16* __restrict__ A,
                                                        const f16* __restrict__ Bt,
                                                        const float* __restrict__ bias,
                                                        float* __restrict__ Cout) {
    __shared__ f16 As3[3 * 17408];
    __shared__ f16 Bs3[3 * 8704];
    const int tid = threadIdx.x;
    const int wid = tid >> 6, lane = tid & 63;
    const int wm = wid >> 1, wn = wid & 1;
    const int lr = lane & 15, lg = lane >> 4;
    const int row0 = blockIdx.x * 256, col0 = blockIdx.y * 128;

    f32x4 acc[4][4];
#pragma unroll
    for (int m = 0; m < 4; ++m)
#pragma unroll
        for (int n = 0; n < 4; ++n) acc[m][n] = (f32x4){0.f, 0.f, 0.f, 0.f};

    G256_PIPELINE(A, Bt)

#pragma unroll
    for (int m = 0; m < 4; ++m) {
#pragma unroll
        for (int n = 0; n < 4; ++n) {
            int col = col0 + wn * 64 + n * 16 + lr;
            float bv = bias[col];
#pragma unroll
            for (int r = 0; r < 4; ++r) {
                int row = row0 + wm * 64 + m * 16 + lg * 4 + r;
                Cout[(size_t)row * 1024 + col] = acc[m][n][r] + bv;
            }
        }
    }
}

// ------------------------------ attention -----------------------------------
// 8 waves x 32 q-rows (256 q/block), FULL K range, no split-K. Round-18
// arithmetic: LDS-read pipe was ~95% busy (64 ds_read_b128 x 12cy = 768cy of
// the 806cy per block-tile). 32 q/wave makes the same 8 LDS fragment reads
// serve 2x the MFMA work -> LDS pipe ~50%. __launch_bounds__(512,4) keeps the
// VGPR cap at 128 — the verified regime where this 2-qt body allocates 64
// VGPR (r13/r14/r16); r12/r19 both proved caps <128 spill the accumulators.
// Grid 512 = 2 blocks/CU = 16 waves/CU. Waves 0-3 stage K, 4-7 stage V;
// lane-major fragments (0 conflicts); 4-buffer pair staging, 1 barrier/pair;
// m folded into MFMA C-init; lazy max vs const THR.
#define ATTN_TILE(Kc, Vc)                                                     \
    do {                                                                      \
        f16x8 ka0 = *(const f16x8*)&(Kc)[fo];                                 \
        f16x8 ka1 = *(const f16x8*)&(Kc)[fo + 1024];                          \
        f16x8 ka2 = *(const f16x8*)&(Kc)[fo + 512];                           \
        f16x8 ka3 = *(const f16x8*)&(Kc)[fo + 1536];                          \
        f32x4 st[2][2];                                                       \
        _Pragma("unroll")                                                     \
        for (int qt = 0; qt < 2; ++qt) {                                      \
            float nm = -m_r[qt];                                              \
            f32x4 z = (f32x4){nm, nm, nm, nm};                                \
            z = MFMA(ka0, qf[qt][0], z);                                      \
            z = MFMA(ka1, qf[qt][1], z);                                      \
            st[qt][0] = z;                                                    \
            f32x4 z2 = (f32x4){nm, nm, nm, nm};                               \
            z2 = MFMA(ka2, qf[qt][0], z2);                                    \
            z2 = MFMA(ka3, qf[qt][1], z2);                                    \
            st[qt][1] = z2;                                                   \
        }                                                                     \
        f16x8 vv0 = *(const f16x8*)&(Vc)[fo];                                 \
        f16x8 vv1 = *(const f16x8*)&(Vc)[fo + 512];                           \
        f16x8 vv2 = *(const f16x8*)&(Vc)[fo + 1024];                          \
        f16x8 vv3 = *(const f16x8*)&(Vc)[fo + 1536];                          \
        {                                                                     \
            float lm[2];                                                      \
            _Pragma("unroll")                                                 \
            for (int qt = 0; qt < 2; ++qt) {                                  \
                float a0 = fmaxf(fmaxf(st[qt][0][0], st[qt][0][1]), st[qt][0][2]); \
                float b0 = fmaxf(fmaxf(st[qt][0][3], st[qt][1][0]), st[qt][1][1]); \
                float c0 = fmaxf(fmaxf(st[qt][1][2], st[qt][1][3]), a0);      \
                lm[qt] = fmaxf(b0, c0);                                       \
            }                                                                 \
            if (__any((lm[0] > THR) || (lm[1] > THR))) {                      \
                _Pragma("unroll")                                             \
                for (int qt = 0; qt < 2; ++qt) {                              \
                    float t0v = lm[qt];                                       \
                    t0v = fmaxf(t0v, __shfl_xor(t0v, 16, 64));                \
                    t0v = fmaxf(t0v, __shfl_xor(t0v, 32, 64));                \
                    float delta = fmaxf(0.f, t0v);                            \
                    float alpha = __builtin_amdgcn_exp2f(-delta);             \
                    _Pragma("unroll")                                         \
                    for (int m = 0; m < 4; ++m)                               \
                        _Pragma("unroll")                                     \
                        for (int r = 0; r < 4; ++r) o[qt][m][r] *= alpha;     \
                    l_p[qt] *= alpha;                                         \
                    m_r[qt] += delta;                                         \
                    _Pragma("unroll")                                         \
                    for (int t = 0; t < 2; ++t)                               \
                        _Pragma("unroll")                                     \
                        for (int r = 0; r < 4; ++r) st[qt][t][r] -= delta;    \
                }                                                             \
            }                                                                 \
        }                                                                     \
        f16x8 pf[2];                                                          \
        _Pragma("unroll")                                                     \
        for (int qt = 0; qt < 2; ++qt) {                                      \
            float ps = 0.f;                                                   \
            union { uint32_t u[4]; f16x8 v; } bb;                             \
            _Pragma("unroll")                                                 \
            for (int t = 0; t < 2; ++t)                                       \
                _Pragma("unroll")                                             \
                for (int pr = 0; pr < 2; ++pr) {                              \
                    float e0 = __builtin_amdgcn_exp2f(st[qt][t][2 * pr]);     \
                    float e1 = __builtin_amdgcn_exp2f(st[qt][t][2 * pr + 1]); \
                    ps += e0 + e1;                                            \
                    auto hp = __builtin_amdgcn_cvt_pkrtz(e0, e1);             \
                    bb.u[t * 2 + pr] = __builtin_bit_cast(uint32_t, hp);      \
                }                                                             \
            l_p[qt] += ps;                                                    \
            pf[qt] = bb.v;                                                    \
        }                                                                     \
        _Pragma("unroll")                                                     \
        for (int qt = 0; qt < 2; ++qt) {                                      \
            o[qt][0] = MFMA(vv0, pf[qt], o[qt][0]);                           \
            o[qt][1] = MFMA(vv1, pf[qt], o[qt][1]);                           \
            o[qt][2] = MFMA(vv2, pf[qt], o[qt][2]);                           \
            o[qt][3] = MFMA(vv3, pf[qt], o[qt][3]);                           \
        }                                                                     \
    } while (0)

__global__ __launch_bounds__(512, 4) void k_attn(const f16* __restrict__ q,
                                                 const f16* __restrict__ k2,
                                                 const f16* __restrict__ v2,
                                                 f16* __restrict__ cat) {
    const int g = blockIdx.x;                 // 0..511
    const int xcd = g & 7, i = g >> 3;        // i: 0..63
    const int bh = xcd * 8 + (i >> 3);        // 8 bh per XCD (K/V L2 locality)
    const int qb = i & 7;                     // 8 q-blocks of 256 rows
    const int b = bh >> 4, h = bh & 15;

    const int tid = threadIdx.x, wid = tid >> 6, lane = tid & 63;
    const int lr = lane & 15, lg = lane >> 4;
    const int qw = qb * 256 + wid * 32;       // this wave's 32 q-rows

    __shared__ f16 Ks[4][2048];
    __shared__ f16 Vs[4][2048];

    const float THR = 8.0f;

    // Q fragments (hoisted; pre-scaled by 1/8*log2e in the q GEMM)
    f16x8 qf[2][2];
#pragma unroll
    for (int qt = 0; qt < 2; ++qt)
#pragma unroll
        for (int hf = 0; hf < 2; ++hf)
            qf[qt][hf] = *(const f16x8*)&q[((size_t)bh * 2048 + qw + qt * 16 + lr) * 64 + hf * 32 + lg * 8];

    const f16* kt = k2 + (size_t)bh * 131072;     // tile stride 2048 elements
    const f16* vt = v2 + (size_t)bh * 131072;
    const bool sgK = (tid < 256);                 // waves 0-3 stage K, 4-7 stage V
    const int so2 = (tid & 255) * 8;              // stage offset within a tile
    const int fo = lane * 8;                      // lane-major fragment offset

    f32x4 o[2][4];
#pragma unroll
    for (int qt = 0; qt < 2; ++qt)
#pragma unroll
        for (int m = 0; m < 4; ++m) o[qt][m] = (f32x4){0.f, 0.f, 0.f, 0.f};
    float m_r[2] = {0.f, 0.f}, l_p[2] = {0.f, 0.f};

    // prologue: stage tiles 0,1
    if (sgK) {
        gload_lds16(kt + so2, &Ks[0][so2]);
        gload_lds16(kt + 2048 + so2, &Ks[1][so2]);
    } else {
        gload_lds16(vt + so2, &Vs[0][so2]);
        gload_lds16(vt + 2048 + so2, &Vs[1][so2]);
    }
    __syncthreads();

    // pair loop: compute tiles (2pp, 2pp+1); stage (2pp+2, 2pp+3); 1 barrier/pair
    for (int pp = 0; pp < 32; ++pp) {
        const int t0 = 2 * pp;
        const int ba = t0 & 3, bb2 = (t0 + 1) & 3;
        const int bc = (t0 + 2) & 3, bd = (t0 + 3) & 3;

        // tail stages read up to 2 tiles past this bh's range: adjacent ws
        // buffer data — in-bounds of d_ws, never consumed
        if (sgK) {
            gload_lds16(kt + (size_t)(t0 + 2) * 2048 + so2, &Ks[bc][so2]);
            gload_lds16(kt + (size_t)(t0 + 3) * 2048 + so2, &Ks[bd][so2]);
        } else {
            gload_lds16(vt + (size_t)(t0 + 2) * 2048 + so2, &Vs[bc][so2]);
            gload_lds16(vt + (size_t)(t0 + 3) * 2048 + so2, &Vs[bd][so2]);
        }

        ATTN_TILE(&Ks[ba][0], &Vs[ba][0]);
        ATTN_TILE(&Ks[bb2][0], &Vs[bb2][0]);

        __syncthreads();   // buffer handoff (stage covered by 2 tiles of compute)
    }

    // epilogue: reduce per-lane l partials, normalize, store
#pragma unroll
    for (int qt = 0; qt < 2; ++qt) {
        float l = l_p[qt];
        l += __shfl_xor(l, 16, 64);
        l += __shfl_xor(l, 32, 64);
        float inv = 1.f / l;
        size_t cb = ((size_t)b * 2048 + qw + qt * 16 + lr) * 1024 + h * 64 + lg * 4;
#pragma unroll
        for (int m = 0; m < 4; ++m) {
            f16x4 ov;
#pragma unroll
            for (int r = 0; r < 4; ++r) ov[r] = (f16)(o[qt][m][r] * inv);
            *(f16x4*)&cat[cb + m * 16] = ov;
        }
    }
}

// ---------------------------------------------------------------------------
extern "C" void kernel_launch(void* const* d_in, const int* in_sizes, int n_in,
                              void* d_out, int out_size, void* d_ws, size_t ws_size,
                              hipStream_t stream) {
    const float* Q  = (const float*)d_in[0];
    const float* K  = (const float*)d_in[1];
    const float* V  = (const float*)d_in[2];
    const float* Wq = (const float*)d_in[3];
    const float* bq = (const float*)d_in[4];
    const float* Wk = (const float*)d_in[5];
    const float* bk = (const float*)d_in[6];
    const float* Wv = (const float*)d_in[7];
    const float* bv = (const float*)d_in[8];
    const float* Wo = (const float*)d_in[9];
    const float* bo = (const float*)d_in[10];

    char* ws = (char*)d_ws;
    size_t off = 0;
    auto alloc = [&](size_t bytes) {
        char* p = ws + off;
        off += (bytes + 255) & ~(size_t)255;
        return p;
    };
    f16* Qh  = (f16*)alloc(8192ULL * 1024 * 2);
    f16* Kh  = (f16*)alloc(8192ULL * 1024 * 2);
    f16* Vh  = (f16*)alloc(8192ULL * 1024 * 2);
    f16* WT  = (f16*)alloc(3ULL * 1024 * 1024 * 2);   // WqT|WkT|WvT contiguous
    f16* WoT = (f16*)alloc(1024ULL * 1024 * 2);
    f16* qb  = (f16*)alloc(8192ULL * 1024 * 2);   // head-major [(b,h)][s][64]
    f16* kb2 = (f16*)alloc(8192ULL * 1024 * 2);   // [bh][tile] lane-major perm K
    f16* vb2 = (f16*)alloc(8192ULL * 1024 * 2);   // [bh][tile] lane-major V^T
    f16* cat = (f16*)alloc(8192ULL * 1024 * 2);   // [B*S][H*VS]

    k_convert3<<<6144, 256, 0, stream>>>(Q, K, V, Qh, Kh, Vh);
    k_transpose_all<<<1024, 256, 0, stream>>>(Wq, Wk, Wv, Wo, WT, WoT);

    const float SC = 0.125f * 1.44269504089f;   // 1/sqrt(64) * log2(e), folded into q
    k_gemm_qkv256<<<dim3(32, 24), 512, 0, stream>>>(Qh, Kh, Vh, WT, bq, bk, bv,
                                                    qb, kb2, vb2, SC);

    k_attn<<<512, 512, 0, stream>>>(qb, kb2, vb2, cat);

    k_gemm_out256<<<dim3(32, 8), 512, 0, stream>>>(cat, WoT, bo, (float*)d_out);
}

// Round 21
// 190.742 us; speedup vs baseline: 2.5794x; 1.0147x over previous
//
#include <hip/hip_runtime.h>
#include <hip/hip_fp16.h>
#include <cstdint>
#include <cstddef>

typedef _Float16 f16;
typedef _Float16 f16x8 __attribute__((ext_vector_type(8)));
typedef _Float16 f16x4 __attribute__((ext_vector_type(4)));
typedef float    f32x4 __attribute__((ext_vector_type(4)));

#define MFMA(a, b, c) __builtin_amdgcn_mfma_f32_16x16x32_f16(a, b, c, 0, 0, 0)

// B=4, S=2048, D=1024, H=16, KS=VS=64, O=1024.

__device__ __forceinline__ void gload_lds16(const f16* g, f16* l) {
    __builtin_amdgcn_global_load_lds(
        (const __attribute__((address_space(1))) void*)g,
        (__attribute__((address_space(3))) void*)l, 16, 0, 0);
}

// ------------------- fp32 -> fp16 convert (Q,K,V fused) ----------------------
__global__ void k_convert3(const float* __restrict__ Q, const float* __restrict__ K,
                           const float* __restrict__ V, f16* __restrict__ Qh,
                           f16* __restrict__ Kh, f16* __restrict__ Vh) {
    const int seg = blockIdx.x >> 11;              // 0..2 (2048 blocks each)
    const int lb  = blockIdx.x & 2047;
    const float* src = seg == 0 ? Q : (seg == 1 ? K : V);
    f16* dst = seg == 0 ? Qh : (seg == 1 ? Kh : Vh);
    int i = lb * blockDim.x + threadIdx.x;
    for (; i < 2097152; i += 524288) {             // n4 = 8192*1024/4
        float4 v = ((const float4*)src)[i];
        f16x4 h;
        h[0] = (f16)v.x; h[1] = (f16)v.y; h[2] = (f16)v.z; h[3] = (f16)v.w;
        ((f16x4*)dst)[i] = h;
    }
}

// ---------------- weight transpose + convert to fp16 (all 4 fused) ----------
__global__ void k_transpose_all(const float* __restrict__ Wq, const float* __restrict__ Wk,
                                const float* __restrict__ Wv, const float* __restrict__ Wo,
                                f16* __restrict__ WT, f16* __restrict__ WoT) {
    __shared__ float T[64][65];
    const int bx = blockIdx.x;
    const int widx = bx >> 8, sub = bx & 255;
    const int nb = sub >> 4, db = sub & 15;
    const int tid = threadIdx.x;
    const float* W = widx == 0 ? Wq : (widx == 1 ? Wk : (widx == 2 ? Wv : Wo));
    f16* Wt = (widx < 3) ? (WT + (size_t)widx * 1048576) : WoT;
    const float* src = (widx < 3) ? (W + nb * 65536 + db * 4096)
                                  : (W + db * 65536 + nb * 64);
    const int rstride = (widx < 3) ? 64 : 1024;
    {
        int nn = tid & 63, d0 = tid >> 6;
#pragma unroll
        for (int p = 0; p < 16; ++p) {
            int dd = p * 4 + d0;
            T[dd][nn] = src[dd * rstride + nn];
        }
    }
    __syncthreads();
    {
        int dd = tid & 63, n0 = tid >> 6;
#pragma unroll
        for (int p = 0; p < 16; ++p) {
            int nn = p * 4 + n0;
            Wt[(size_t)(nb * 64 + nn) * 1024 + db * 64 + dd] = (f16)T[dd][nn];
        }
    }
}

// ---------------------- 256x128-tile GEMM building blocks --------------------
#define G256_STAGE(AD, BD, ASRC, BSRC, KT)                                      \
    do {                                                                        \
        int ktc = (KT);                                                         \
        _Pragma("unroll")                                                       \
        for (int i2 = 0; i2 < 4; ++i2) {                                        \
            int gA = wid * 4 + i2;                                              \
            gload_lds16(&(ASRC)[(size_t)(row0 + gA * 8 + (lane >> 3)) * 1024    \
                                + ktc * 64 + (lane & 7) * 8],                   \
                        &(AD)[(gA * 68 + lane) * 8]);                           \
        }                                                                       \
        _Pragma("unroll")                                                       \
        for (int i2 = 0; i2 < 2; ++i2) {                                        \
            int gB = wid * 2 + i2;                                              \
            gload_lds16(&(BSRC)[(size_t)(col0 + gB * 8 + (lane >> 3)) * 1024    \
                                + ktc * 64 + (lane & 7) * 8],                   \
                        &(BD)[(gB * 68 + lane) * 8]);                           \
        }                                                                       \
    } while (0)

#define G256_COMPUTE(AB, BB)                                                    \
    do {                                                                        \
        _Pragma("unroll")                                                       \
        for (int kk = 0; kk < 2; ++kk) {                                        \
            f16x8 af[4], bf[4];                                                 \
            _Pragma("unroll")                                                   \
            for (int m = 0; m < 4; ++m) {                                       \
                int rw = wm * 64 + m * 16 + lr;                                 \
                af[m] = *(const f16x8*)&(AB)[((rw >> 3) * 68 + (rw & 7) * 8     \
                                              + kk * 4 + lg) * 8];              \
            }                                                                   \
            _Pragma("unroll")                                                   \
            for (int n = 0; n < 4; ++n) {                                       \
                int rw = wn * 64 + n * 16 + lr;                                 \
                bf[n] = *(const f16x8*)&(BB)[((rw >> 3) * 68 + (rw & 7) * 8     \
                                              + kk * 4 + lg) * 8];              \
            }                                                                   \
            _Pragma("unroll")                                                   \
            for (int m = 0; m < 4; ++m)                                         \
                _Pragma("unroll")                                               \
                for (int n = 0; n < 4; ++n)                                     \
                    acc[m][n] = MFMA(af[m], bf[n], acc[m][n]);                  \
        }                                                                       \
    } while (0)

#define G256_PIPELINE(ASRC, BSRC)                                              \
    int cur = 0, nx1 = 1, nx2 = 2;                                             \
    G256_STAGE(As3, Bs3, ASRC, BSRC, 0);                                       \
    for (int t = 0; t < 16; ++t) {                                             \
        int tn = t < 15 ? t + 1 : 15;                                          \
        G256_STAGE(As3 + nx1 * 17408, Bs3 + nx1 * 8704, ASRC, BSRC, tn);       \
        asm volatile("s_waitcnt vmcnt(6)" ::: "memory");                       \
        __builtin_amdgcn_sched_barrier(0);                                     \
        __builtin_amdgcn_s_barrier();                                          \
        __builtin_amdgcn_sched_barrier(0);                                     \
        const f16* Ab = As3 + cur * 17408;                                     \
        const f16* Bb = Bs3 + cur * 8704;                                      \
        G256_COMPUTE(Ab, Bb);                                                  \
        int tmp = cur; cur = nx1; nx1 = nx2; nx2 = tmp;                        \
    }

// --------------------------- fused q/k/v GEMM (256x128) ----------------------
__global__ __launch_bounds__(512, 1) void k_gemm_qkv256(
    const f16* __restrict__ Qh, const f16* __restrict__ Kh, const f16* __restrict__ Vh,
    const f16* __restrict__ WT, const float* __restrict__ bq,
    const float* __restrict__ bk, const float* __restrict__ bv,
    f16* __restrict__ qout, f16* __restrict__ kout, f16* __restrict__ vout, float SC) {
    __shared__ f16 As3[3 * 17408];
    __shared__ f16 Bs3[3 * 8704];
    const int yy = blockIdx.y;
    const int seg = yy >> 3;
    const f16* A    = seg == 0 ? Qh : (seg == 1 ? Kh : Vh);
    const f16* Bt   = WT + (size_t)seg * 1048576;
    const float* bias = seg == 0 ? bq : (seg == 1 ? bk : bv);
    const float scale = seg == 0 ? SC : 1.0f;

    const int tid = threadIdx.x;
    const int wid = tid >> 6, lane = tid & 63;
    const int wm = wid >> 1, wn = wid & 1;
    const int lr = lane & 15, lg = lane >> 4;
    const int row0 = blockIdx.x * 256, col0 = (yy & 7) * 128;

    f32x4 acc[4][4];
#pragma unroll
    for (int m = 0; m < 4; ++m)
#pragma unroll
        for (int n = 0; n < 4; ++n) acc[m][n] = (f32x4){0.f, 0.f, 0.f, 0.f};

    G256_PIPELINE(A, Bt)

#pragma unroll
    for (int m = 0; m < 4; ++m) {
#pragma unroll
        for (int n = 0; n < 4; ++n) {
            int col = col0 + wn * 64 + n * 16 + lr;
            float bv_ = bias[col];
            int rowb = row0 + wm * 64 + m * 16 + lg * 4;
            int srow = rowb & 2047;
            if (seg == 0) {
#pragma unroll
                for (int r = 0; r < 4; ++r) {
                    int row = rowb + r;
                    size_t a = ((size_t)((row >> 11) * 16 + (col >> 6)) * 2048 + (row & 2047)) * 64 + (col & 63);
                    qout[a] = (f16)((acc[m][n][r] + bv_) * scale);
                }
            } else if (seg == 1) {
                int ks5 = srow & 31;
                int p0 = ((ks5 >> 2) & 1) * 16 + (ks5 >> 3) * 4 + (ks5 & 3);
                size_t abase = (size_t)((rowb >> 11) * 16 + (col >> 6)) * 131072
                             + (size_t)(srow >> 5) * 2048
                             + (size_t)(p0 >> 4) * 512
                             + (size_t)((col & 63) >> 5) * 1024
                             + (size_t)((col & 31) >> 3) * 128
                             + (col & 7);
#pragma unroll
                for (int r = 0; r < 4; ++r)
                    kout[abase + (size_t)((p0 & 15) + r) * 8] = (f16)(acc[m][n][r] + bv_);
            } else {
                size_t a = (size_t)((rowb >> 11) * 16 + (col >> 6)) * 131072
                         + (size_t)(srow >> 5) * 2048
                         + (size_t)((col & 63) >> 4) * 512
                         + (size_t)((srow & 31) >> 3) * 128
                         + (size_t)(col & 15) * 8
                         + (srow & 7);
                f16x4 ov;
#pragma unroll
                for (int r = 0; r < 4; ++r) ov[r] = (f16)(acc[m][n][r] + bv_);
                *(f16x4*)&vout[a] = ov;
            }
        }
    }
}

// ------------------------------ output GEMM (256x128) ------------------------
__global__ __launch_bounds__(512, 1) void k_gemm_out256(const f16* __restrict__ A,
                                                        const f16* __restrict__ Bt,
                                                        const float* __restrict__ bias,
                                                        float* __restrict__ Cout) {
    __shared__ f16 As3[3 * 17408];
    __shared__ f16 Bs3[3 * 8704];
    const int tid = threadIdx.x;
    const int wid = tid >> 6, lane = tid & 63;
    const int wm = wid >> 1, wn = wid & 1;
    const int lr = lane & 15, lg = lane >> 4;
    const int row0 = blockIdx.x * 256, col0 = blockIdx.y * 128;

    f32x4 acc[4][4];
#pragma unroll
    for (int m = 0; m < 4; ++m)
#pragma unroll
        for (int n = 0; n < 4; ++n) acc[m][n] = (f32x4){0.f, 0.f, 0.f, 0.f};

    G256_PIPELINE(A, Bt)

#pragma unroll
    for (int m = 0; m < 4; ++m) {
#pragma unroll
        for (int n = 0; n < 4; ++n) {
            int col = col0 + wn * 64 + n * 16 + lr;
            float bv = bias[col];
#pragma unroll
            for (int r = 0; r < 4; ++r) {
                int row = row0 + wm * 64 + m * 16 + lg * 4 + r;
                Cout[(size_t)row * 1024 + col] = acc[m][n][r] + bv;
            }
        }
    }
}

// ------------------------------ attention -----------------------------------
// r20 structure (8 waves x 32 q-rows, full K, (512,4) VGPR cap 128, lane-major
// fragments, 4-buffer pair staging) + ones-row MFMA for l (r8/r12-verified):
// the matrix pipe (35% busy) computes the P row-sums, deleting the 32 serial
// v_add_f32 per pair (VALU was the top pipe at ~53%) and the epilogue shuffle
// reduce. ol rescaled by alpha in the rare defer-max branch; l = ol[qt][0]
// lane-local at the end. VGPR ~72, under the 128 cap (r12/r19 spill lesson).
#define ATTN_TILE(Kc, Vc)                                                     \
    do {                                                                      \
        f16x8 ka0 = *(const f16x8*)&(Kc)[fo];                                 \
        f16x8 ka1 = *(const f16x8*)&(Kc)[fo + 1024];                          \
        f16x8 ka2 = *(const f16x8*)&(Kc)[fo + 512];                           \
        f16x8 ka3 = *(const f16x8*)&(Kc)[fo + 1536];                          \
        f32x4 st[2][2];                                                       \
        _Pragma("unroll")                                                     \
        for (int qt = 0; qt < 2; ++qt) {                                      \
            float nm = -m_r[qt];                                              \
            f32x4 z = (f32x4){nm, nm, nm, nm};                                \
            z = MFMA(ka0, qf[qt][0], z);                                      \
            z = MFMA(ka1, qf[qt][1], z);                                      \
            st[qt][0] = z;                                                    \
            f32x4 z2 = (f32x4){nm, nm, nm, nm};                               \
            z2 = MFMA(ka2, qf[qt][0], z2);                                    \
            z2 = MFMA(ka3, qf[qt][1], z2);                                    \
            st[qt][1] = z2;                                                   \
        }                                                                     \
        f16x8 vv0 = *(const f16x8*)&(Vc)[fo];                                 \
        f16x8 vv1 = *(const f16x8*)&(Vc)[fo + 512];                           \
        f16x8 vv2 = *(const f16x8*)&(Vc)[fo + 1024];                          \
        f16x8 vv3 = *(const f16x8*)&(Vc)[fo + 1536];                          \
        {                                                                     \
            float lm[2];                                                      \
            _Pragma("unroll")                                                 \
            for (int qt = 0; qt < 2; ++qt) {                                  \
                float a0 = fmaxf(fmaxf(st[qt][0][0], st[qt][0][1]), st[qt][0][2]); \
                float b0 = fmaxf(fmaxf(st[qt][0][3], st[qt][1][0]), st[qt][1][1]); \
                float c0 = fmaxf(fmaxf(st[qt][1][2], st[qt][1][3]), a0);      \
                lm[qt] = fmaxf(b0, c0);                                       \
            }                                                                 \
            if (__any((lm[0] > THR) || (lm[1] > THR))) {                      \
                _Pragma("unroll")                                             \
                for (int qt = 0; qt < 2; ++qt) {                              \
                    float t0v = lm[qt];                                       \
                    t0v = fmaxf(t0v, __shfl_xor(t0v, 16, 64));                \
                    t0v = fmaxf(t0v, __shfl_xor(t0v, 32, 64));                \
                    float delta = fmaxf(0.f, t0v);                            \
                    float alpha = __builtin_amdgcn_exp2f(-delta);             \
                    _Pragma("unroll")                                         \
                    for (int m = 0; m < 4; ++m)                               \
                        _Pragma("unroll")                                     \
                        for (int r = 0; r < 4; ++r) o[qt][m][r] *= alpha;     \
                    _Pragma("unroll")                                         \
                    for (int r = 0; r < 4; ++r) ol[qt][r] *= alpha;           \
                    m_r[qt] += delta;                                         \
                    _Pragma("unroll")                                         \
                    for (int t = 0; t < 2; ++t)                               \
                        _Pragma("unroll")                                     \
                        for (int r = 0; r < 4; ++r) st[qt][t][r] -= delta;    \
                }                                                             \
            }                                                                 \
        }                                                                     \
        f16x8 pf[2];                                                          \
        _Pragma("unroll")                                                     \
        for (int qt = 0; qt < 2; ++qt) {                                      \
            union { uint32_t u[4]; f16x8 v; } bb;                             \
            _Pragma("unroll")                                                 \
            for (int t = 0; t < 2; ++t)                                       \
                _Pragma("unroll")                                             \
                for (int pr = 0; pr < 2; ++pr) {                              \
                    float e0 = __builtin_amdgcn_exp2f(st[qt][t][2 * pr]);     \
                    float e1 = __builtin_amdgcn_exp2f(st[qt][t][2 * pr + 1]); \
                    auto hp = __builtin_amdgcn_cvt_pkrtz(e0, e1);             \
                    bb.u[t * 2 + pr] = __builtin_bit_cast(uint32_t, hp);      \
                }                                                             \
            pf[qt] = bb.v;                                                    \
        }                                                                     \
        _Pragma("unroll")                                                     \
        for (int qt = 0; qt < 2; ++qt) {                                      \
            o[qt][0] = MFMA(vv0, pf[qt], o[qt][0]);                           \
            o[qt][1] = MFMA(vv1, pf[qt], o[qt][1]);                           \
            o[qt][2] = MFMA(vv2, pf[qt], o[qt][2]);                           \
            o[qt][3] = MFMA(vv3, pf[qt], o[qt][3]);                           \
            ol[qt]   = MFMA(ones, pf[qt], ol[qt]);                            \
        }                                                                     \
    } while (0)

__global__ __launch_bounds__(512, 4) void k_attn(const f16* __restrict__ q,
                                                 const f16* __restrict__ k2,
                                                 const f16* __restrict__ v2,
                                                 f16* __restrict__ cat) {
    const int g = blockIdx.x;                 // 0..511
    const int xcd = g & 7, i = g >> 3;        // i: 0..63
    const int bh = xcd * 8 + (i >> 3);        // 8 bh per XCD (K/V L2 locality)
    const int qb = i & 7;                     // 8 q-blocks of 256 rows
    const int b = bh >> 4, h = bh & 15;

    const int tid = threadIdx.x, wid = tid >> 6, lane = tid & 63;
    const int lr = lane & 15, lg = lane >> 4;
    const int qw = qb * 256 + wid * 32;       // this wave's 32 q-rows

    __shared__ f16 Ks[4][2048];
    __shared__ f16 Vs[4][2048];

    const float THR = 8.0f;

    // Q fragments (hoisted; pre-scaled by 1/8*log2e in the q GEMM)
    f16x8 qf[2][2];
#pragma unroll
    for (int qt = 0; qt < 2; ++qt)
#pragma unroll
        for (int hf = 0; hf < 2; ++hf)
            qf[qt][hf] = *(const f16x8*)&q[((size_t)bh * 2048 + qw + qt * 16 + lr) * 64 + hf * 32 + lg * 8];

    const f16* kt = k2 + (size_t)bh * 131072;     // tile stride 2048 elements
    const f16* vt = v2 + (size_t)bh * 131072;
    const bool sgK = (tid < 256);                 // waves 0-3 stage K, 4-7 stage V
    const int so2 = (tid & 255) * 8;              // stage offset within a tile
    const int fo = lane * 8;                      // lane-major fragment offset

    f16x8 ones;
#pragma unroll
    for (int j = 0; j < 8; ++j) ones[j] = (f16)1.0f;

    f32x4 o[2][4], ol[2];
#pragma unroll
    for (int qt = 0; qt < 2; ++qt) {
#pragma unroll
        for (int m = 0; m < 4; ++m) o[qt][m] = (f32x4){0.f, 0.f, 0.f, 0.f};
        ol[qt] = (f32x4){0.f, 0.f, 0.f, 0.f};
    }
    float m_r[2] = {0.f, 0.f};

    // prologue: stage tiles 0,1
    if (sgK) {
        gload_lds16(kt + so2, &Ks[0][so2]);
        gload_lds16(kt + 2048 + so2, &Ks[1][so2]);
    } else {
        gload_lds16(vt + so2, &Vs[0][so2]);
        gload_lds16(vt + 2048 + so2, &Vs[1][so2]);
    }
    __syncthreads();

    // pair loop: compute tiles (2pp, 2pp+1); stage (2pp+2, 2pp+3); 1 barrier/pair
    for (int pp = 0; pp < 32; ++pp) {
        const int t0 = 2 * pp;
        const int ba = t0 & 3, bb2 = (t0 + 1) & 3;
        const int bc = (t0 + 2) & 3, bd = (t0 + 3) & 3;

        // tail stages read up to 2 tiles past this bh's range: adjacent ws
        // buffer data — in-bounds of d_ws, never consumed
        if (sgK) {
            gload_lds16(kt + (size_t)(t0 + 2) * 2048 + so2, &Ks[bc][so2]);
            gload_lds16(kt + (size_t)(t0 + 3) * 2048 + so2, &Ks[bd][so2]);
        } else {
            gload_lds16(vt + (size_t)(t0 + 2) * 2048 + so2, &Vs[bc][so2]);
            gload_lds16(vt + (size_t)(t0 + 3) * 2048 + so2, &Vs[bd][so2]);
        }

        ATTN_TILE(&Ks[ba][0], &Vs[ba][0]);
        ATTN_TILE(&Ks[bb2][0], &Vs[bb2][0]);

        __syncthreads();   // buffer handoff (stage covered by 2 tiles of compute)
    }

    // epilogue: l is lane-local (ones-MFMA put the full row sum in every reg)
#pragma unroll
    for (int qt = 0; qt < 2; ++qt) {
        float inv = 1.f / ol[qt][0];
        size_t cb = ((size_t)b * 2048 + qw + qt * 16 + lr) * 1024 + h * 64 + lg * 4;
#pragma unroll
        for (int m = 0; m < 4; ++m) {
            f16x4 ov;
#pragma unroll
            for (int r = 0; r < 4; ++r) ov[r] = (f16)(o[qt][m][r] * inv);
            *(f16x4*)&cat[cb + m * 16] = ov;
        }
    }
}

// ---------------------------------------------------------------------------
extern "C" void kernel_launch(void* const* d_in, const int* in_sizes, int n_in,
                              void* d_out, int out_size, void* d_ws, size_t ws_size,
                              hipStream_t stream) {
    const float* Q  = (const float*)d_in[0];
    const float* K  = (const float*)d_in[1];
    const float* V  = (const float*)d_in[2];
    const float* Wq = (const float*)d_in[3];
    const float* bq = (const float*)d_in[4];
    const float* Wk = (const float*)d_in[5];
    const float* bk = (const float*)d_in[6];
    const float* Wv = (const float*)d_in[7];
    const float* bv = (const float*)d_in[8];
    const float* Wo = (const float*)d_in[9];
    const float* bo = (const float*)d_in[10];

    char* ws = (char*)d_ws;
    size_t off = 0;
    auto alloc = [&](size_t bytes) {
        char* p = ws + off;
        off += (bytes + 255) & ~(size_t)255;
        return p;
    };
    f16* Qh  = (f16*)alloc(8192ULL * 1024 * 2);
    f16* Kh  = (f16*)alloc(8192ULL * 1024 * 2);
    f16* Vh  = (f16*)alloc(8192ULL * 1024 * 2);
    f16* WT  = (f16*)alloc(3ULL * 1024 * 1024 * 2);   // WqT|WkT|WvT contiguous
    f16* WoT = (f16*)alloc(1024ULL * 1024 * 2);
    f16* qb  = (f16*)alloc(8192ULL * 1024 * 2);   // head-major [(b,h)][s][64]
    f16* kb2 = (f16*)alloc(8192ULL * 1024 * 2);   // [bh][tile] lane-major perm K
    f16* vb2 = (f16*)alloc(8192ULL * 1024 * 2);   // [bh][tile] lane-major V^T
    f16* cat = (f16*)alloc(8192ULL * 1024 * 2);   // [B*S][H*VS]

    k_convert3<<<6144, 256, 0, stream>>>(Q, K, V, Qh, Kh, Vh);
    k_transpose_all<<<1024, 256, 0, stream>>>(Wq, Wk, Wv, Wo, WT, WoT);

    const float SC = 0.125f * 1.44269504089f;   // 1/sqrt(64) * log2(e), folded into q
    k_gemm_qkv256<<<dim3(32, 24), 512, 0, stream>>>(Qh, Kh, Vh, WT, bq, bk, bv,
                                                    qb, kb2, vb2, SC);

    k_attn<<<512, 512, 0, stream>>>(qb, kb2, vb2, cat);

    k_gemm_out256<<<dim3(32, 8), 512, 0, stream>>>(cat, WoT, bo, (float*)d_out);
}

// Round 22
// 190.195 us; speedup vs baseline: 2.5868x; 1.0029x over previous
//
#include <hip/hip_runtime.h>
#include <hip/hip_fp16.h>
#include <cstdint>
#include <cstddef>

typedef _Float16 f16;
typedef _Float16 f16x8 __attribute__((ext_vector_type(8)));
typedef _Float16 f16x4 __attribute__((ext_vector_type(4)));
typedef float    f32x4 __attribute__((ext_vector_type(4)));

#define MFMA(a, b, c) __builtin_amdgcn_mfma_f32_16x16x32_f16(a, b, c, 0, 0, 0)

// B=4, S=2048, D=1024, H=16, KS=VS=64, O=1024.

__device__ __forceinline__ void gload_lds16(const f16* g, f16* l) {
    __builtin_amdgcn_global_load_lds(
        (const __attribute__((address_space(1))) void*)g,
        (__attribute__((address_space(3))) void*)l, 16, 0, 0);
}

// ------------------- fp32 -> fp16 convert (Q,K,V fused) ----------------------
__global__ void k_convert3(const float* __restrict__ Q, const float* __restrict__ K,
                           const float* __restrict__ V, f16* __restrict__ Qh,
                           f16* __restrict__ Kh, f16* __restrict__ Vh) {
    const int seg = blockIdx.x >> 11;              // 0..2 (2048 blocks each)
    const int lb  = blockIdx.x & 2047;
    const float* src = seg == 0 ? Q : (seg == 1 ? K : V);
    f16* dst = seg == 0 ? Qh : (seg == 1 ? Kh : Vh);
    int i = lb * blockDim.x + threadIdx.x;
    for (; i < 2097152; i += 524288) {             // n4 = 8192*1024/4
        float4 v = ((const float4*)src)[i];
        f16x4 h;
        h[0] = (f16)v.x; h[1] = (f16)v.y; h[2] = (f16)v.z; h[3] = (f16)v.w;
        ((f16x4*)dst)[i] = h;
    }
}

// ---------------- weight transpose + convert to fp16 (all 4 fused) ----------
__global__ void k_transpose_all(const float* __restrict__ Wq, const float* __restrict__ Wk,
                                const float* __restrict__ Wv, const float* __restrict__ Wo,
                                f16* __restrict__ WT, f16* __restrict__ WoT) {
    __shared__ float T[64][65];
    const int bx = blockIdx.x;
    const int widx = bx >> 8, sub = bx & 255;
    const int nb = sub >> 4, db = sub & 15;
    const int tid = threadIdx.x;
    const float* W = widx == 0 ? Wq : (widx == 1 ? Wk : (widx == 2 ? Wv : Wo));
    f16* Wt = (widx < 3) ? (WT + (size_t)widx * 1048576) : WoT;
    const float* src = (widx < 3) ? (W + nb * 65536 + db * 4096)
                                  : (W + db * 65536 + nb * 64);
    const int rstride = (widx < 3) ? 64 : 1024;
    {
        int nn = tid & 63, d0 = tid >> 6;
#pragma unroll
        for (int p = 0; p < 16; ++p) {
            int dd = p * 4 + d0;
            T[dd][nn] = src[dd * rstride + nn];
        }
    }
    __syncthreads();
    {
        int dd = tid & 63, n0 = tid >> 6;
#pragma unroll
        for (int p = 0; p < 16; ++p) {
            int nn = p * 4 + n0;
            Wt[(size_t)(nb * 64 + nn) * 1024 + db * 64 + dd] = (f16)T[dd][nn];
        }
    }
}

// ---------------------- 256x128-tile GEMM building blocks --------------------
#define G256_STAGE(AD, BD, ASRC, BSRC, KT)                                      \
    do {                                                                        \
        int ktc = (KT);                                                         \
        _Pragma("unroll")                                                       \
        for (int i2 = 0; i2 < 4; ++i2) {                                        \
            int gA = wid * 4 + i2;                                              \
            gload_lds16(&(ASRC)[(size_t)(row0 + gA * 8 + (lane >> 3)) * 1024    \
                                + ktc * 64 + (lane & 7) * 8],                   \
                        &(AD)[(gA * 68 + lane) * 8]);                           \
        }                                                                       \
        _Pragma("unroll")                                                       \
        for (int i2 = 0; i2 < 2; ++i2) {                                        \
            int gB = wid * 2 + i2;                                              \
            gload_lds16(&(BSRC)[(size_t)(col0 + gB * 8 + (lane >> 3)) * 1024    \
                                + ktc * 64 + (lane & 7) * 8],                   \
                        &(BD)[(gB * 68 + lane) * 8]);                           \
        }                                                                       \
    } while (0)

#define G256_COMPUTE(AB, BB)                                                    \
    do {                                                                        \
        _Pragma("unroll")                                                       \
        for (int kk = 0; kk < 2; ++kk) {                                        \
            f16x8 af[4], bf[4];                                                 \
            _Pragma("unroll")                                                   \
            for (int m = 0; m < 4; ++m) {                                       \
                int rw = wm * 64 + m * 16 + lr;                                 \
                af[m] = *(const f16x8*)&(AB)[((rw >> 3) * 68 + (rw & 7) * 8     \
                                              + kk * 4 + lg) * 8];              \
            }                                                                   \
            _Pragma("unroll")                                                   \
            for (int n = 0; n < 4; ++n) {                                       \
                int rw = wn * 64 + n * 16 + lr;                                 \
                bf[n] = *(const f16x8*)&(BB)[((rw >> 3) * 68 + (rw & 7) * 8     \
                                              + kk * 4 + lg) * 8];              \
            }                                                                   \
            _Pragma("unroll")                                                   \
            for (int m = 0; m < 4; ++m)                                         \
                _Pragma("unroll")                                               \
                for (int n = 0; n < 4; ++n)                                     \
                    acc[m][n] = MFMA(af[m], bf[n], acc[m][n]);                  \
        }                                                                       \
    } while (0)

#define G256_PIPELINE(ASRC, BSRC)                                              \
    int cur = 0, nx1 = 1, nx2 = 2;                                             \
    G256_STAGE(As3, Bs3, ASRC, BSRC, 0);                                       \
    for (int t = 0; t < 16; ++t) {                                             \
        int tn = t < 15 ? t + 1 : 15;                                          \
        G256_STAGE(As3 + nx1 * 17408, Bs3 + nx1 * 8704, ASRC, BSRC, tn);       \
        asm volatile("s_waitcnt vmcnt(6)" ::: "memory");                       \
        __builtin_amdgcn_sched_barrier(0);                                     \
        __builtin_amdgcn_s_barrier();                                          \
        __builtin_amdgcn_sched_barrier(0);                                     \
        const f16* Ab = As3 + cur * 17408;                                     \
        const f16* Bb = Bs3 + cur * 8704;                                      \
        G256_COMPUTE(Ab, Bb);                                                  \
        int tmp = cur; cur = nx1; nx1 = nx2; nx2 = tmp;                        \
    }

// --------------------------- fused q/k/v GEMM (256x128) ----------------------
__global__ __launch_bounds__(512, 1) void k_gemm_qkv256(
    const f16* __restrict__ Qh, const f16* __restrict__ Kh, const f16* __restrict__ Vh,
    const f16* __restrict__ WT, const float* __restrict__ bq,
    const float* __restrict__ bk, const float* __restrict__ bv,
    f16* __restrict__ qout, f16* __restrict__ kout, f16* __restrict__ vout, float SC) {
    __shared__ f16 As3[3 * 17408];
    __shared__ f16 Bs3[3 * 8704];
    const int yy = blockIdx.y;
    const int seg = yy >> 3;
    const f16* A    = seg == 0 ? Qh : (seg == 1 ? Kh : Vh);
    const f16* Bt   = WT + (size_t)seg * 1048576;
    const float* bias = seg == 0 ? bq : (seg == 1 ? bk : bv);
    const float scale = seg == 0 ? SC : 1.0f;

    const int tid = threadIdx.x;
    const int wid = tid >> 6, lane = tid & 63;
    const int wm = wid >> 1, wn = wid & 1;
    const int lr = lane & 15, lg = lane >> 4;
    const int row0 = blockIdx.x * 256, col0 = (yy & 7) * 128;

    f32x4 acc[4][4];
#pragma unroll
    for (int m = 0; m < 4; ++m)
#pragma unroll
        for (int n = 0; n < 4; ++n) acc[m][n] = (f32x4){0.f, 0.f, 0.f, 0.f};

    G256_PIPELINE(A, Bt)

#pragma unroll
    for (int m = 0; m < 4; ++m) {
#pragma unroll
        for (int n = 0; n < 4; ++n) {
            int col = col0 + wn * 64 + n * 16 + lr;
            float bv_ = bias[col];
            int rowb = row0 + wm * 64 + m * 16 + lg * 4;
            int srow = rowb & 2047;
            if (seg == 0) {
#pragma unroll
                for (int r = 0; r < 4; ++r) {
                    int row = rowb + r;
                    size_t a = ((size_t)((row >> 11) * 16 + (col >> 6)) * 2048 + (row & 2047)) * 64 + (col & 63);
                    qout[a] = (f16)((acc[m][n][r] + bv_) * scale);
                }
            } else if (seg == 1) {
                int ks5 = srow & 31;
                int p0 = ((ks5 >> 2) & 1) * 16 + (ks5 >> 3) * 4 + (ks5 & 3);
                size_t abase = (size_t)((rowb >> 11) * 16 + (col >> 6)) * 131072
                             + (size_t)(srow >> 5) * 2048
                             + (size_t)(p0 >> 4) * 512
                             + (size_t)((col & 63) >> 5) * 1024
                             + (size_t)((col & 31) >> 3) * 128
                             + (col & 7);
#pragma unroll
                for (int r = 0; r < 4; ++r)
                    kout[abase + (size_t)((p0 & 15) + r) * 8] = (f16)(acc[m][n][r] + bv_);
            } else {
                size_t a = (size_t)((rowb >> 11) * 16 + (col >> 6)) * 131072
                         + (size_t)(srow >> 5) * 2048
                         + (size_t)((col & 63) >> 4) * 512
                         + (size_t)((srow & 31) >> 3) * 128
                         + (size_t)(col & 15) * 8
                         + (srow & 7);
                f16x4 ov;
#pragma unroll
                for (int r = 0; r < 4; ++r) ov[r] = (f16)(acc[m][n][r] + bv_);
                *(f16x4*)&vout[a] = ov;
            }
        }
    }
}

// ------------------------------ output GEMM (256x128) ------------------------
__global__ __launch_bounds__(512, 1) void k_gemm_out256(const f16* __restrict__ A,
                                                        const f16* __restrict__ Bt,
                                                        const float* __restrict__ bias,
                                                        float* __restrict__ Cout) {
    __shared__ f16 As3[3 * 17408];
    __shared__ f16 Bs3[3 * 8704];
    const int tid = threadIdx.x;
    const int wid = tid >> 6, lane = tid & 63;
    const int wm = wid >> 1, wn = wid & 1;
    const int lr = lane & 15, lg = lane >> 4;
    const int row0 = blockIdx.x * 256, col0 = blockIdx.y * 128;

    f32x4 acc[4][4];
#pragma unroll
    for (int m = 0; m < 4; ++m)
#pragma unroll
        for (int n = 0; n < 4; ++n) acc[m][n] = (f32x4){0.f, 0.f, 0.f, 0.f};

    G256_PIPELINE(A, Bt)

#pragma unroll
    for (int m = 0; m < 4; ++m) {
#pragma unroll
        for (int n = 0; n < 4; ++n) {
            int col = col0 + wn * 64 + n * 16 + lr;
            float bv = bias[col];
#pragma unroll
            for (int r = 0; r < 4; ++r) {
                int row = row0 + wm * 64 + m * 16 + lg * 4 + r;
                Cout[(size_t)row * 1024 + col] = acc[m][n][r] + bv;
            }
        }
    }
}

// ------------------------------ attention -----------------------------------
// r21 structure + WAVE-STAGGERED pair order: odd waves process each staged
// pair in reverse (online softmax is order-invariant; both tiles are staged
// before the pair starts; all softmax state is wave-local). Round-21
// diagnosis: MFMA 42% + VALU 52% but elapsed = 2x max pipe — lockstep waves
// hit the same pipe simultaneously. Stagger puts half the waves in the
// MFMA phase while the other half runs softmax VALU -> pipes co-schedule
// (m114). With role diversity, setprio(1) around MFMA clusters is in its
// T5-positive regime (m218b/m224; m190's null was lockstep).
#define ATTN_TILE(Kc, Vc)                                                     \
    do {                                                                      \
        f16x8 ka0 = *(const f16x8*)&(Kc)[fo];                                 \
        f16x8 ka1 = *(const f16x8*)&(Kc)[fo + 1024];                          \
        f16x8 ka2 = *(const f16x8*)&(Kc)[fo + 512];                           \
        f16x8 ka3 = *(const f16x8*)&(Kc)[fo + 1536];                          \
        f32x4 st[2][2];                                                       \
        __builtin_amdgcn_s_setprio(1);                                        \
        _Pragma("unroll")                                                     \
        for (int qt = 0; qt < 2; ++qt) {                                      \
            float nm = -m_r[qt];                                              \
            f32x4 z = (f32x4){nm, nm, nm, nm};                                \
            z = MFMA(ka0, qf[qt][0], z);                                      \
            z = MFMA(ka1, qf[qt][1], z);                                      \
            st[qt][0] = z;                                                    \
            f32x4 z2 = (f32x4){nm, nm, nm, nm};                               \
            z2 = MFMA(ka2, qf[qt][0], z2);                                    \
            z2 = MFMA(ka3, qf[qt][1], z2);                                    \
            st[qt][1] = z2;                                                   \
        }                                                                     \
        __builtin_amdgcn_s_setprio(0);                                        \
        f16x8 vv0 = *(const f16x8*)&(Vc)[fo];                                 \
        f16x8 vv1 = *(const f16x8*)&(Vc)[fo + 512];                           \
        f16x8 vv2 = *(const f16x8*)&(Vc)[fo + 1024];                          \
        f16x8 vv3 = *(const f16x8*)&(Vc)[fo + 1536];                          \
        {                                                                     \
            float lm[2];                                                      \
            _Pragma("unroll")                                                 \
            for (int qt = 0; qt < 2; ++qt) {                                  \
                float a0 = fmaxf(fmaxf(st[qt][0][0], st[qt][0][1]), st[qt][0][2]); \
                float b0 = fmaxf(fmaxf(st[qt][0][3], st[qt][1][0]), st[qt][1][1]); \
                float c0 = fmaxf(fmaxf(st[qt][1][2], st[qt][1][3]), a0);      \
                lm[qt] = fmaxf(b0, c0);                                       \
            }                                                                 \
            if (__any((lm[0] > THR) || (lm[1] > THR))) {                      \
                _Pragma("unroll")                                             \
                for (int qt = 0; qt < 2; ++qt) {                              \
                    float t0v = lm[qt];                                       \
                    t0v = fmaxf(t0v, __shfl_xor(t0v, 16, 64));                \
                    t0v = fmaxf(t0v, __shfl_xor(t0v, 32, 64));                \
                    float delta = fmaxf(0.f, t0v);                            \
                    float alpha = __builtin_amdgcn_exp2f(-delta);             \
                    _Pragma("unroll")                                         \
                    for (int m = 0; m < 4; ++m)                               \
                        _Pragma("unroll")                                     \
                        for (int r = 0; r < 4; ++r) o[qt][m][r] *= alpha;     \
                    _Pragma("unroll")                                         \
                    for (int r = 0; r < 4; ++r) ol[qt][r] *= alpha;           \
                    m_r[qt] += delta;                                         \
                    _Pragma("unroll")                                         \
                    for (int t = 0; t < 2; ++t)                               \
                        _Pragma("unroll")                                     \
                        for (int r = 0; r < 4; ++r) st[qt][t][r] -= delta;    \
                }                                                             \
            }                                                                 \
        }                                                                     \
        f16x8 pf[2];                                                          \
        _Pragma("unroll")                                                     \
        for (int qt = 0; qt < 2; ++qt) {                                      \
            union { uint32_t u[4]; f16x8 v; } bb;                             \
            _Pragma("unroll")                                                 \
            for (int t = 0; t < 2; ++t)                                       \
                _Pragma("unroll")                                             \
                for (int pr = 0; pr < 2; ++pr) {                              \
                    float e0 = __builtin_amdgcn_exp2f(st[qt][t][2 * pr]);     \
                    float e1 = __builtin_amdgcn_exp2f(st[qt][t][2 * pr + 1]); \
                    auto hp = __builtin_amdgcn_cvt_pkrtz(e0, e1);             \
                    bb.u[t * 2 + pr] = __builtin_bit_cast(uint32_t, hp);      \
                }                                                             \
            pf[qt] = bb.v;                                                    \
        }                                                                     \
        __builtin_amdgcn_s_setprio(1);                                        \
        _Pragma("unroll")                                                     \
        for (int qt = 0; qt < 2; ++qt) {                                      \
            o[qt][0] = MFMA(vv0, pf[qt], o[qt][0]);                           \
            o[qt][1] = MFMA(vv1, pf[qt], o[qt][1]);                           \
            o[qt][2] = MFMA(vv2, pf[qt], o[qt][2]);                           \
            o[qt][3] = MFMA(vv3, pf[qt], o[qt][3]);                           \
            ol[qt]   = MFMA(ones, pf[qt], ol[qt]);                            \
        }                                                                     \
        __builtin_amdgcn_s_setprio(0);                                        \
    } while (0)

__global__ __launch_bounds__(512, 4) void k_attn(const f16* __restrict__ q,
                                                 const f16* __restrict__ k2,
                                                 const f16* __restrict__ v2,
                                                 f16* __restrict__ cat) {
    const int g = blockIdx.x;                 // 0..511
    const int xcd = g & 7, i = g >> 3;        // i: 0..63
    const int bh = xcd * 8 + (i >> 3);        // 8 bh per XCD (K/V L2 locality)
    const int qb = i & 7;                     // 8 q-blocks of 256 rows
    const int b = bh >> 4, h = bh & 15;

    const int tid = threadIdx.x, wid = tid >> 6, lane = tid & 63;
    const int lr = lane & 15, lg = lane >> 4;
    const int qw = qb * 256 + wid * 32;       // this wave's 32 q-rows

    __shared__ f16 Ks[4][2048];
    __shared__ f16 Vs[4][2048];

    const float THR = 8.0f;

    // Q fragments (hoisted; pre-scaled by 1/8*log2e in the q GEMM)
    f16x8 qf[2][2];
#pragma unroll
    for (int qt = 0; qt < 2; ++qt)
#pragma unroll
        for (int hf = 0; hf < 2; ++hf)
            qf[qt][hf] = *(const f16x8*)&q[((size_t)bh * 2048 + qw + qt * 16 + lr) * 64 + hf * 32 + lg * 8];

    const f16* kt = k2 + (size_t)bh * 131072;     // tile stride 2048 elements
    const f16* vt = v2 + (size_t)bh * 131072;
    const bool sgK = (tid < 256);                 // waves 0-3 stage K, 4-7 stage V
    const int so2 = (tid & 255) * 8;              // stage offset within a tile
    const int fo = lane * 8;                      // lane-major fragment offset

    f16x8 ones;
#pragma unroll
    for (int j = 0; j < 8; ++j) ones[j] = (f16)1.0f;

    f32x4 o[2][4], ol[2];
#pragma unroll
    for (int qt = 0; qt < 2; ++qt) {
#pragma unroll
        for (int m = 0; m < 4; ++m) o[qt][m] = (f32x4){0.f, 0.f, 0.f, 0.f};
        ol[qt] = (f32x4){0.f, 0.f, 0.f, 0.f};
    }
    float m_r[2] = {0.f, 0.f};

    // prologue: stage tiles 0,1
    if (sgK) {
        gload_lds16(kt + so2, &Ks[0][so2]);
        gload_lds16(kt + 2048 + so2, &Ks[1][so2]);
    } else {
        gload_lds16(vt + so2, &Vs[0][so2]);
        gload_lds16(vt + 2048 + so2, &Vs[1][so2]);
    }
    __syncthreads();

    // pair loop: compute tiles (2pp, 2pp+1); stage (2pp+2, 2pp+3); 1 barrier/pair.
    // Odd waves process the pair in REVERSE order (order-invariant math) so
    // half the waves are in the MFMA phase while the other half runs softmax.
    const bool rev = (wid & 1);
    for (int pp = 0; pp < 32; ++pp) {
        const int t0 = 2 * pp;
        const int ba = t0 & 3, bb2 = (t0 + 1) & 3;
        const int bc = (t0 + 2) & 3, bd = (t0 + 3) & 3;

        // tail stages read up to 2 tiles past this bh's range: adjacent ws
        // buffer data — in-bounds of d_ws, never consumed
        if (sgK) {
            gload_lds16(kt + (size_t)(t0 + 2) * 2048 + so2, &Ks[bc][so2]);
            gload_lds16(kt + (size_t)(t0 + 3) * 2048 + so2, &Ks[bd][so2]);
        } else {
            gload_lds16(vt + (size_t)(t0 + 2) * 2048 + so2, &Vs[bc][so2]);
            gload_lds16(vt + (size_t)(t0 + 3) * 2048 + so2, &Vs[bd][so2]);
        }

        if (rev) {
            ATTN_TILE(&Ks[bb2][0], &Vs[bb2][0]);
            ATTN_TILE(&Ks[ba][0], &Vs[ba][0]);
        } else {
            ATTN_TILE(&Ks[ba][0], &Vs[ba][0]);
            ATTN_TILE(&Ks[bb2][0], &Vs[bb2][0]);
        }

        __syncthreads();   // buffer handoff (stage covered by 2 tiles of compute)
    }

    // epilogue: l is lane-local (ones-MFMA put the full row sum in every reg)
#pragma unroll
    for (int qt = 0; qt < 2; ++qt) {
        float inv = 1.f / ol[qt][0];
        size_t cb = ((size_t)b * 2048 + qw + qt * 16 + lr) * 1024 + h * 64 + lg * 4;
#pragma unroll
        for (int m = 0; m < 4; ++m) {
            f16x4 ov;
#pragma unroll
            for (int r = 0; r < 4; ++r) ov[r] = (f16)(o[qt][m][r] * inv);
            *(f16x4*)&cat[cb + m * 16] = ov;
        }
    }
}

// ---------------------------------------------------------------------------
extern "C" void kernel_launch(void* const* d_in, const int* in_sizes, int n_in,
                              void* d_out, int out_size, void* d_ws, size_t ws_size,
                              hipStream_t stream) {
    const float* Q  = (const float*)d_in[0];
    const float* K  = (const float*)d_in[1];
    const float* V  = (const float*)d_in[2];
    const float* Wq = (const float*)d_in[3];
    const float* bq = (const float*)d_in[4];
    const float* Wk = (const float*)d_in[5];
    const float* bk = (const float*)d_in[6];
    const float* Wv = (const float*)d_in[7];
    const float* bv = (const float*)d_in[8];
    const float* Wo = (const float*)d_in[9];
    const float* bo = (const float*)d_in[10];

    char* ws = (char*)d_ws;
    size_t off = 0;
    auto alloc = [&](size_t bytes) {
        char* p = ws + off;
        off += (bytes + 255) & ~(size_t)255;
        return p;
    };
    f16* Qh  = (f16*)alloc(8192ULL * 1024 * 2);
    f16* Kh  = (f16*)alloc(8192ULL * 1024 * 2);
    f16* Vh  = (f16*)alloc(8192ULL * 1024 * 2);
    f16* WT  = (f16*)alloc(3ULL * 1024 * 1024 * 2);   // WqT|WkT|WvT contiguous
    f16* WoT = (f16*)alloc(1024ULL * 1024 * 2);
    f16* qb  = (f16*)alloc(8192ULL * 1024 * 2);   // head-major [(b,h)][s][64]
    f16* kb2 = (f16*)alloc(8192ULL * 1024 * 2);   // [bh][tile] lane-major perm K
    f16* vb2 = (f16*)alloc(8192ULL * 1024 * 2);   // [bh][tile] lane-major V^T
    f16* cat = (f16*)alloc(8192ULL * 1024 * 2);   // [B*S][H*VS]

    k_convert3<<<6144, 256, 0, stream>>>(Q, K, V, Qh, Kh, Vh);
    k_transpose_all<<<1024, 256, 0, stream>>>(Wq, Wk, Wv, Wo, WT, WoT);

    const float SC = 0.125f * 1.44269504089f;   // 1/sqrt(64) * log2(e), folded into q
    k_gemm_qkv256<<<dim3(32, 24), 512, 0, stream>>>(Qh, Kh, Vh, WT, bq, bk, bv,
                                                    qb, kb2, vb2, SC);

    k_attn<<<512, 512, 0, stream>>>(qb, kb2, vb2, cat);

    k_gemm_out256<<<dim3(32, 8), 512, 0, stream>>>(cat, WoT, bo, (float*)d_out);
}

// Round 23
// 183.382 us; speedup vs baseline: 2.6830x; 1.0372x over previous
//
#include <hip/hip_runtime.h>
#include <hip/hip_fp16.h>
#include <cstdint>
#include <cstddef>

typedef _Float16 f16;
typedef _Float16 f16x8 __attribute__((ext_vector_type(8)));
typedef _Float16 f16x4 __attribute__((ext_vector_type(4)));
typedef float    f32x4 __attribute__((ext_vector_type(4)));

#define MFMA(a, b, c) __builtin_amdgcn_mfma_f32_16x16x32_f16(a, b, c, 0, 0, 0)

// B=4, S=2048, D=1024, H=16, KS=VS=64, O=1024.

__device__ __forceinline__ void gload_lds16(const f16* g, f16* l) {
    __builtin_amdgcn_global_load_lds(
        (const __attribute__((address_space(1))) void*)g,
        (__attribute__((address_space(3))) void*)l, 16, 0, 0);
}

// ---------------- weight transpose + convert to fp16 (all 4 fused) ----------
__global__ void k_transpose_all(const float* __restrict__ Wq, const float* __restrict__ Wk,
                                const float* __restrict__ Wv, const float* __restrict__ Wo,
                                f16* __restrict__ WT, f16* __restrict__ WoT) {
    __shared__ float T[64][65];
    const int bx = blockIdx.x;
    const int widx = bx >> 8, sub = bx & 255;
    const int nb = sub >> 4, db = sub & 15;
    const int tid = threadIdx.x;
    const float* W = widx == 0 ? Wq : (widx == 1 ? Wk : (widx == 2 ? Wv : Wo));
    f16* Wt = (widx < 3) ? (WT + (size_t)widx * 1048576) : WoT;
    const float* src = (widx < 3) ? (W + nb * 65536 + db * 4096)
                                  : (W + db * 65536 + nb * 64);
    const int rstride = (widx < 3) ? 64 : 1024;
    {
        int nn = tid & 63, d0 = tid >> 6;
#pragma unroll
        for (int p = 0; p < 16; ++p) {
            int dd = p * 4 + d0;
            T[dd][nn] = src[dd * rstride + nn];
        }
    }
    __syncthreads();
    {
        int dd = tid & 63, n0 = tid >> 6;
#pragma unroll
        for (int p = 0; p < 16; ++p) {
            int nn = p * 4 + n0;
            Wt[(size_t)(nb * 64 + nn) * 1024 + db * 64 + dd] = (f16)T[dd][nn];
        }
    }
}

// ---------------------- 256x128-tile GEMM building blocks --------------------
// LDS chunk layout (16B chunks): chunk(row, cc) = (row>>3)*68 + (row&7)*8 + cc
#define G256_STAGE(AD, BD, ASRC, BSRC, KT)                                      \
    do {                                                                        \
        int ktc = (KT);                                                         \
        _Pragma("unroll")                                                       \
        for (int i2 = 0; i2 < 4; ++i2) {                                        \
            int gA = wid * 4 + i2;                                              \
            gload_lds16(&(ASRC)[(size_t)(row0 + gA * 8 + (lane >> 3)) * 1024    \
                                + ktc * 64 + (lane & 7) * 8],                   \
                        &(AD)[(gA * 68 + lane) * 8]);                           \
        }                                                                       \
        _Pragma("unroll")                                                       \
        for (int i2 = 0; i2 < 2; ++i2) {                                        \
            int gB = wid * 2 + i2;                                              \
            gload_lds16(&(BSRC)[(size_t)(col0 + gB * 8 + (lane >> 3)) * 1024    \
                                + ktc * 64 + (lane & 7) * 8],                   \
                        &(BD)[(gB * 68 + lane) * 8]);                           \
        }                                                                       \
    } while (0)

#define G256_STAGE_B(BD, BSRC, KT)                                             \
    do {                                                                        \
        int ktc = (KT);                                                         \
        _Pragma("unroll")                                                       \
        for (int i2 = 0; i2 < 2; ++i2) {                                        \
            int gB = wid * 2 + i2;                                              \
            gload_lds16(&(BSRC)[(size_t)(col0 + gB * 8 + (lane >> 3)) * 1024    \
                                + ktc * 64 + (lane & 7) * 8],                   \
                        &(BD)[(gB * 68 + lane) * 8]);                           \
        }                                                                       \
    } while (0)

// A-side fused f32->f16 staging (replaces the separate convert kernel):
// issue 2x global_load_dwordx4 per chunk into regs; later cvt_pkrtz + ds_write.
#define QKV_ISSUE_A(KT)                                                         \
    do {                                                                        \
        int ktc = (KT);                                                         \
        _Pragma("unroll")                                                       \
        for (int i2 = 0; i2 < 4; ++i2) {                                        \
            int gA = wid * 4 + i2;                                              \
            const float* p = &Af[(size_t)(row0 + gA * 8 + (lane >> 3)) * 1024   \
                                 + ktc * 64 + (lane & 7) * 8];                  \
            alo[i2] = *(const float4*)p;                                        \
            ahi[i2] = *(const float4*)(p + 4);                                  \
        }                                                                       \
    } while (0)

#define QKV_WRITE_A(AD)                                                         \
    do {                                                                        \
        _Pragma("unroll")                                                       \
        for (int i2 = 0; i2 < 4; ++i2) {                                        \
            int gA = wid * 4 + i2;                                              \
            union { uint32_t u[4]; f16x8 v; } hh;                               \
            hh.u[0] = __builtin_bit_cast(uint32_t,                              \
                        __builtin_amdgcn_cvt_pkrtz(alo[i2].x, alo[i2].y));      \
            hh.u[1] = __builtin_bit_cast(uint32_t,                              \
                        __builtin_amdgcn_cvt_pkrtz(alo[i2].z, alo[i2].w));      \
            hh.u[2] = __builtin_bit_cast(uint32_t,                              \
                        __builtin_amdgcn_cvt_pkrtz(ahi[i2].x, ahi[i2].y));      \
            hh.u[3] = __builtin_bit_cast(uint32_t,                              \
                        __builtin_amdgcn_cvt_pkrtz(ahi[i2].z, ahi[i2].w));      \
            *(f16x8*)&(AD)[(gA * 68 + lane) * 8] = hh.v;                        \
        }                                                                       \
    } while (0)

#define G256_COMPUTE(AB, BB)                                                    \
    do {                                                                        \
        _Pragma("unroll")                                                       \
        for (int kk = 0; kk < 2; ++kk) {                                        \
            f16x8 af[4], bf[4];                                                 \
            _Pragma("unroll")                                                   \
            for (int m = 0; m < 4; ++m) {                                       \
                int rw = wm * 64 + m * 16 + lr;                                 \
                af[m] = *(const f16x8*)&(AB)[((rw >> 3) * 68 + (rw & 7) * 8     \
                                              + kk * 4 + lg) * 8];              \
            }                                                                   \
            _Pragma("unroll")                                                   \
            for (int n = 0; n < 4; ++n) {                                       \
                int rw = wn * 64 + n * 16 + lr;                                 \
                bf[n] = *(const f16x8*)&(BB)[((rw >> 3) * 68 + (rw & 7) * 8     \
                                              + kk * 4 + lg) * 8];              \
            }                                                                   \
            _Pragma("unroll")                                                   \
            for (int m = 0; m < 4; ++m)                                         \
                _Pragma("unroll")                                               \
                for (int n = 0; n < 4; ++n)                                     \
                    acc[m][n] = MFMA(af[m], bf[n], acc[m][n]);                  \
        }                                                                       \
    } while (0)

#define G256_PIPELINE(ASRC, BSRC)                                              \
    int cur = 0, nx1 = 1, nx2 = 2;                                             \
    G256_STAGE(As3, Bs3, ASRC, BSRC, 0);                                       \
    for (int t = 0; t < 16; ++t) {                                             \
        int tn = t < 15 ? t + 1 : 15;                                          \
        G256_STAGE(As3 + nx1 * 17408, Bs3 + nx1 * 8704, ASRC, BSRC, tn);       \
        asm volatile("s_waitcnt vmcnt(6)" ::: "memory");                       \
        __builtin_amdgcn_sched_barrier(0);                                     \
        __builtin_amdgcn_s_barrier();                                          \
        __builtin_amdgcn_sched_barrier(0);                                     \
        const f16* Ab = As3 + cur * 17408;                                     \
        const f16* Bb = Bs3 + cur * 8704;                                      \
        G256_COMPUTE(Ab, Bb);                                                  \
        int tmp = cur; cur = nx1; nx1 = nx2; nx2 = tmp;                        \
    }

// --------------------------- fused q/k/v GEMM (256x128, f32 A) ---------------
// A read DIRECTLY as f32 (Q/K/V inputs) with reg-staged cvt_pkrtz + ds_write —
// eliminates the separate convert kernel (~24us HBM round-trip). B (weights,
// f16) stays global_load_lds. Per iter: compute(t) -> vmcnt(0) [A(t+1) regs +
// B(t+1) LDS landed; issued last iter = full compute phase of cover] ->
// ds_write A(t+1) -> issue B(t+2)+A(t+2) -> lgkmcnt(0) -> barrier. 3-buffer
// rotation keeps WAR safe (overwrite separated by 2 barriers).
__global__ __launch_bounds__(512, 1) void k_gemm_qkv256(
    const float* __restrict__ Qf, const float* __restrict__ Kf, const float* __restrict__ Vf,
    const f16* __restrict__ WT, const float* __restrict__ bq,
    const float* __restrict__ bk, const float* __restrict__ bv,
    f16* __restrict__ qout, f16* __restrict__ kout, f16* __restrict__ vout, float SC) {
    __shared__ f16 As3[3 * 17408];
    __shared__ f16 Bs3[3 * 8704];
    const int yy = blockIdx.y;
    const int seg = yy >> 3;
    const float* Af = seg == 0 ? Qf : (seg == 1 ? Kf : Vf);
    const f16* Bt   = WT + (size_t)seg * 1048576;
    const float* bias = seg == 0 ? bq : (seg == 1 ? bk : bv);
    const float scale = seg == 0 ? SC : 1.0f;

    const int tid = threadIdx.x;
    const int wid = tid >> 6, lane = tid & 63;
    const int wm = wid >> 1, wn = wid & 1;
    const int lr = lane & 15, lg = lane >> 4;
    const int row0 = blockIdx.x * 256, col0 = (yy & 7) * 128;

    f32x4 acc[4][4];
#pragma unroll
    for (int m = 0; m < 4; ++m)
#pragma unroll
        for (int n = 0; n < 4; ++n) acc[m][n] = (f32x4){0.f, 0.f, 0.f, 0.f};

    float4 alo[4], ahi[4];

    // prologue: stage tile 0 (A via regs), start tile 1
    G256_STAGE_B(Bs3, Bt, 0);
    QKV_ISSUE_A(0);
    asm volatile("s_waitcnt vmcnt(0)" ::: "memory");
    QKV_WRITE_A(As3);
    G256_STAGE_B(Bs3 + 8704, Bt, 1);
    QKV_ISSUE_A(1);
    asm volatile("s_waitcnt lgkmcnt(0)" ::: "memory");
    __builtin_amdgcn_sched_barrier(0);
    __builtin_amdgcn_s_barrier();
    __builtin_amdgcn_sched_barrier(0);

    int cur = 0, nx1 = 1, nx2 = 2;
    for (int t = 0; t < 16; ++t) {
        const f16* Ab = As3 + cur * 17408;
        const f16* Bb = Bs3 + cur * 8704;
        G256_COMPUTE(Ab, Bb);
        int tn2 = t + 2 <= 15 ? t + 2 : 15;      // tail restages tile 15 (unread)
        asm volatile("s_waitcnt vmcnt(0)" ::: "memory");
        __builtin_amdgcn_sched_barrier(0);
        QKV_WRITE_A(As3 + nx1 * 17408);
        G256_STAGE_B(Bs3 + nx2 * 8704, Bt, tn2);
        QKV_ISSUE_A(tn2);
        asm volatile("s_waitcnt lgkmcnt(0)" ::: "memory");
        __builtin_amdgcn_sched_barrier(0);
        __builtin_amdgcn_s_barrier();
        __builtin_amdgcn_sched_barrier(0);
        int tmp = cur; cur = nx1; nx1 = nx2; nx2 = tmp;
    }

#pragma unroll
    for (int m = 0; m < 4; ++m) {
#pragma unroll
        for (int n = 0; n < 4; ++n) {
            int col = col0 + wn * 64 + n * 16 + lr;
            float bv_ = bias[col];
            int rowb = row0 + wm * 64 + m * 16 + lg * 4;
            int srow = rowb & 2047;
            if (seg == 0) {
#pragma unroll
                for (int r = 0; r < 4; ++r) {
                    int row = rowb + r;
                    size_t a = ((size_t)((row >> 11) * 16 + (col >> 6)) * 2048 + (row & 2047)) * 64 + (col & 63);
                    qout[a] = (f16)((acc[m][n][r] + bv_) * scale);
                }
            } else if (seg == 1) {
                int ks5 = srow & 31;
                int p0 = ((ks5 >> 2) & 1) * 16 + (ks5 >> 3) * 4 + (ks5 & 3);
                size_t abase = (size_t)((rowb >> 11) * 16 + (col >> 6)) * 131072
                             + (size_t)(srow >> 5) * 2048
                             + (size_t)(p0 >> 4) * 512
                             + (size_t)((col & 63) >> 5) * 1024
                             + (size_t)((col & 31) >> 3) * 128
                             + (col & 7);
#pragma unroll
                for (int r = 0; r < 4; ++r)
                    kout[abase + (size_t)((p0 & 15) + r) * 8] = (f16)(acc[m][n][r] + bv_);
            } else {
                size_t a = (size_t)((rowb >> 11) * 16 + (col >> 6)) * 131072
                         + (size_t)(srow >> 5) * 2048
                         + (size_t)((col & 63) >> 4) * 512
                         + (size_t)((srow & 31) >> 3) * 128
                         + (size_t)(col & 15) * 8
                         + (srow & 7);
                f16x4 ov;
#pragma unroll
                for (int r = 0; r < 4; ++r) ov[r] = (f16)(acc[m][n][r] + bv_);
                *(f16x4*)&vout[a] = ov;
            }
        }
    }
}

// ------------------------------ output GEMM (256x128) ------------------------
__global__ __launch_bounds__(512, 1) void k_gemm_out256(const f16* __restrict__ A,
                                                        const f16* __restrict__ Bt,
                                                        const float* __restrict__ bias,
                                                        float* __restrict__ Cout) {
    __shared__ f16 As3[3 * 17408];
    __shared__ f16 Bs3[3 * 8704];
    const int tid = threadIdx.x;
    const int wid = tid >> 6, lane = tid & 63;
    const int wm = wid >> 1, wn = wid & 1;
    const int lr = lane & 15, lg = lane >> 4;
    const int row0 = blockIdx.x * 256, col0 = blockIdx.y * 128;

    f32x4 acc[4][4];
#pragma unroll
    for (int m = 0; m < 4; ++m)
#pragma unroll
        for (int n = 0; n < 4; ++n) acc[m][n] = (f32x4){0.f, 0.f, 0.f, 0.f};

    G256_PIPELINE(A, Bt)

#pragma unroll
    for (int m = 0; m < 4; ++m) {
#pragma unroll
        for (int n = 0; n < 4; ++n) {
            int col = col0 + wn * 64 + n * 16 + lr;
            float bv = bias[col];
#pragma unroll
            for (int r = 0; r < 4; ++r) {
                int row = row0 + wm * 64 + m * 16 + lg * 4 + r;
                Cout[(size_t)row * 1024 + col] = acc[m][n][r] + bv;
            }
        }
    }
}

// ------------------------------ attention (r22 winner, unchanged) ------------
#define ATTN_TILE(Kc, Vc)                                                     \
    do {                                                                      \
        f16x8 ka0 = *(const f16x8*)&(Kc)[fo];                                 \
        f16x8 ka1 = *(const f16x8*)&(Kc)[fo + 1024];                          \
        f16x8 ka2 = *(const f16x8*)&(Kc)[fo + 512];                           \
        f16x8 ka3 = *(const f16x8*)&(Kc)[fo + 1536];                          \
        f32x4 st[2][2];                                                       \
        __builtin_amdgcn_s_setprio(1);                                        \
        _Pragma("unroll")                                                     \
        for (int qt = 0; qt < 2; ++qt) {                                      \
            float nm = -m_r[qt];                                              \
            f32x4 z = (f32x4){nm, nm, nm, nm};                                \
            z = MFMA(ka0, qf[qt][0], z);                                      \
            z = MFMA(ka1, qf[qt][1], z);                                      \
            st[qt][0] = z;                                                    \
            f32x4 z2 = (f32x4){nm, nm, nm, nm};                               \
            z2 = MFMA(ka2, qf[qt][0], z2);                                    \
            z2 = MFMA(ka3, qf[qt][1], z2);                                    \
            st[qt][1] = z2;                                                   \
        }                                                                     \
        __builtin_amdgcn_s_setprio(0);                                        \
        f16x8 vv0 = *(const f16x8*)&(Vc)[fo];                                 \
        f16x8 vv1 = *(const f16x8*)&(Vc)[fo + 512];                           \
        f16x8 vv2 = *(const f16x8*)&(Vc)[fo + 1024];                          \
        f16x8 vv3 = *(const f16x8*)&(Vc)[fo + 1536];                          \
        {                                                                     \
            float lm[2];                                                      \
            _Pragma("unroll")                                                 \
            for (int qt = 0; qt < 2; ++qt) {                                  \
                float a0 = fmaxf(fmaxf(st[qt][0][0], st[qt][0][1]), st[qt][0][2]); \
                float b0 = fmaxf(fmaxf(st[qt][0][3], st[qt][1][0]), st[qt][1][1]); \
                float c0 = fmaxf(fmaxf(st[qt][1][2], st[qt][1][3]), a0);      \
                lm[qt] = fmaxf(b0, c0);                                       \
            }                                                                 \
            if (__any((lm[0] > THR) || (lm[1] > THR))) {                      \
                _Pragma("unroll")                                             \
                for (int qt = 0; qt < 2; ++qt) {                              \
                    float t0v = lm[qt];                                       \
                    t0v = fmaxf(t0v, __shfl_xor(t0v, 16, 64));                \
                    t0v = fmaxf(t0v, __shfl_xor(t0v, 32, 64));                \
                    float delta = fmaxf(0.f, t0v);                            \
                    float alpha = __builtin_amdgcn_exp2f(-delta);             \
                    _Pragma("unroll")                                         \
                    for (int m = 0; m < 4; ++m)                               \
                        _Pragma("unroll")                                     \
                        for (int r = 0; r < 4; ++r) o[qt][m][r] *= alpha;     \
                    _Pragma("unroll")                                         \
                    for (int r = 0; r < 4; ++r) ol[qt][r] *= alpha;           \
                    m_r[qt] += delta;                                         \
                    _Pragma("unroll")                                         \
                    for (int t = 0; t < 2; ++t)                               \
                        _Pragma("unroll")                                     \
                        for (int r = 0; r < 4; ++r) st[qt][t][r] -= delta;    \
                }                                                             \
            }                                                                 \
        }                                                                     \
        f16x8 pf[2];                                                          \
        _Pragma("unroll")                                                     \
        for (int qt = 0; qt < 2; ++qt) {                                      \
            union { uint32_t u[4]; f16x8 v; } bb;                             \
            _Pragma("unroll")                                                 \
            for (int t = 0; t < 2; ++t)                                       \
                _Pragma("unroll")                                             \
                for (int pr = 0; pr < 2; ++pr) {                              \
                    float e0 = __builtin_amdgcn_exp2f(st[qt][t][2 * pr]);     \
                    float e1 = __builtin_amdgcn_exp2f(st[qt][t][2 * pr + 1]); \
                    auto hp = __builtin_amdgcn_cvt_pkrtz(e0, e1);             \
                    bb.u[t * 2 + pr] = __builtin_bit_cast(uint32_t, hp);      \
                }                                                             \
            pf[qt] = bb.v;                                                    \
        }                                                                     \
        __builtin_amdgcn_s_setprio(1);                                        \
        _Pragma("unroll")                                                     \
        for (int qt = 0; qt < 2; ++qt) {                                      \
            o[qt][0] = MFMA(vv0, pf[qt], o[qt][0]);                           \
            o[qt][1] = MFMA(vv1, pf[qt], o[qt][1]);                           \
            o[qt][2] = MFMA(vv2, pf[qt], o[qt][2]);                           \
            o[qt][3] = MFMA(vv3, pf[qt], o[qt][3]);                           \
            ol[qt]   = MFMA(ones, pf[qt], ol[qt]);                            \
        }                                                                     \
        __builtin_amdgcn_s_setprio(0);                                        \
    } while (0)

__global__ __launch_bounds__(512, 4) void k_attn(const f16* __restrict__ q,
                                                 const f16* __restrict__ k2,
                                                 const f16* __restrict__ v2,
                                                 f16* __restrict__ cat) {
    const int g = blockIdx.x;                 // 0..511
    const int xcd = g & 7, i = g >> 3;        // i: 0..63
    const int bh = xcd * 8 + (i >> 3);        // 8 bh per XCD (K/V L2 locality)
    const int qb = i & 7;                     // 8 q-blocks of 256 rows
    const int b = bh >> 4, h = bh & 15;

    const int tid = threadIdx.x, wid = tid >> 6, lane = tid & 63;
    const int lr = lane & 15, lg = lane >> 4;
    const int qw = qb * 256 + wid * 32;       // this wave's 32 q-rows

    __shared__ f16 Ks[4][2048];
    __shared__ f16 Vs[4][2048];

    const float THR = 8.0f;

    f16x8 qf[2][2];
#pragma unroll
    for (int qt = 0; qt < 2; ++qt)
#pragma unroll
        for (int hf = 0; hf < 2; ++hf)
            qf[qt][hf] = *(const f16x8*)&q[((size_t)bh * 2048 + qw + qt * 16 + lr) * 64 + hf * 32 + lg * 8];

    const f16* kt = k2 + (size_t)bh * 131072;
    const f16* vt = v2 + (size_t)bh * 131072;
    const bool sgK = (tid < 256);
    const int so2 = (tid & 255) * 8;
    const int fo = lane * 8;

    f16x8 ones;
#pragma unroll
    for (int j = 0; j < 8; ++j) ones[j] = (f16)1.0f;

    f32x4 o[2][4], ol[2];
#pragma unroll
    for (int qt = 0; qt < 2; ++qt) {
#pragma unroll
        for (int m = 0; m < 4; ++m) o[qt][m] = (f32x4){0.f, 0.f, 0.f, 0.f};
        ol[qt] = (f32x4){0.f, 0.f, 0.f, 0.f};
    }
    float m_r[2] = {0.f, 0.f};

    if (sgK) {
        gload_lds16(kt + so2, &Ks[0][so2]);
        gload_lds16(kt + 2048 + so2, &Ks[1][so2]);
    } else {
        gload_lds16(vt + so2, &Vs[0][so2]);
        gload_lds16(vt + 2048 + so2, &Vs[1][so2]);
    }
    __syncthreads();

    const bool rev = (wid & 1);
    for (int pp = 0; pp < 32; ++pp) {
        const int t0 = 2 * pp;
        const int ba = t0 & 3, bb2 = (t0 + 1) & 3;
        const int bc = (t0 + 2) & 3, bd = (t0 + 3) & 3;

        if (sgK) {
            gload_lds16(kt + (size_t)(t0 + 2) * 2048 + so2, &Ks[bc][so2]);
            gload_lds16(kt + (size_t)(t0 + 3) * 2048 + so2, &Ks[bd][so2]);
        } else {
            gload_lds16(vt + (size_t)(t0 + 2) * 2048 + so2, &Vs[bc][so2]);
            gload_lds16(vt + (size_t)(t0 + 3) * 2048 + so2, &Vs[bd][so2]);
        }

        if (rev) {
            ATTN_TILE(&Ks[bb2][0], &Vs[bb2][0]);
            ATTN_TILE(&Ks[ba][0], &Vs[ba][0]);
        } else {
            ATTN_TILE(&Ks[ba][0], &Vs[ba][0]);
            ATTN_TILE(&Ks[bb2][0], &Vs[bb2][0]);
        }

        __syncthreads();
    }

#pragma unroll
    for (int qt = 0; qt < 2; ++qt) {
        float inv = 1.f / ol[qt][0];
        size_t cb = ((size_t)b * 2048 + qw + qt * 16 + lr) * 1024 + h * 64 + lg * 4;
#pragma unroll
        for (int m = 0; m < 4; ++m) {
            f16x4 ov;
#pragma unroll
            for (int r = 0; r < 4; ++r) ov[r] = (f16)(o[qt][m][r] * inv);
            *(f16x4*)&cat[cb + m * 16] = ov;
        }
    }
}

// ---------------------------------------------------------------------------
extern "C" void kernel_launch(void* const* d_in, const int* in_sizes, int n_in,
                              void* d_out, int out_size, void* d_ws, size_t ws_size,
                              hipStream_t stream) {
    const float* Q  = (const float*)d_in[0];
    const float* K  = (const float*)d_in[1];
    const float* V  = (const float*)d_in[2];
    const float* Wq = (const float*)d_in[3];
    const float* bq = (const float*)d_in[4];
    const float* Wk = (const float*)d_in[5];
    const float* bk = (const float*)d_in[6];
    const float* Wv = (const float*)d_in[7];
    const float* bv = (const float*)d_in[8];
    const float* Wo = (const float*)d_in[9];
    const float* bo = (const float*)d_in[10];

    char* ws = (char*)d_ws;
    size_t off = 0;
    auto alloc = [&](size_t bytes) {
        char* p = ws + off;
        off += (bytes + 255) & ~(size_t)255;
        return p;
    };
    f16* WT  = (f16*)alloc(3ULL * 1024 * 1024 * 2);   // WqT|WkT|WvT contiguous
    f16* WoT = (f16*)alloc(1024ULL * 1024 * 2);
    f16* qb  = (f16*)alloc(8192ULL * 1024 * 2);   // head-major [(b,h)][s][64]
    f16* kb2 = (f16*)alloc(8192ULL * 1024 * 2);   // [bh][tile] lane-major perm K
    f16* vb2 = (f16*)alloc(8192ULL * 1024 * 2);   // [bh][tile] lane-major V^T
    f16* cat = (f16*)alloc(8192ULL * 1024 * 2);   // [B*S][H*VS]

    k_transpose_all<<<1024, 256, 0, stream>>>(Wq, Wk, Wv, Wo, WT, WoT);

    const float SC = 0.125f * 1.44269504089f;   // 1/sqrt(64) * log2(e), folded into q
    k_gemm_qkv256<<<dim3(32, 24), 512, 0, stream>>>(Q, K, V, WT, bq, bk, bv,
                                                    qb, kb2, vb2, SC);

    k_attn<<<512, 512, 0, stream>>>(qb, kb2, vb2, cat);

    k_gemm_out256<<<dim3(32, 8), 512, 0, stream>>>(cat, WoT, bo, (float*)d_out);
}